// Round 13
// baseline (186.548 us; speedup 1.0000x reference)
//
#include <hip/hip_runtime.h>
#include <cmath>

#define N_TOK 8192
#define DIM   384
#define NEXP  8
#define HID   1536
#define OUTD  384
#define CAP_MT 72        // 32-row gather tiles per expert (2304 tokens, mean 2048 + 6 sigma)
#define CAP_TOK 2304
#define CAP_TB 18        // 128-row blocks per expert

typedef __attribute__((ext_vector_type(8)))  __bf16 bf16x8;
typedef __attribute__((ext_vector_type(16))) float  f32x16;
typedef __attribute__((ext_vector_type(4)))  float  f32x4;          // nontemporal builtins
typedef __attribute__((ext_vector_type(8)))  unsigned short u16x8;  // nontemporal bf16 loads

__device__ __forceinline__ unsigned short f2bf(float f) {
    unsigned u = __float_as_uint(f);
    u += 0x7FFF + ((u >> 16) & 1);          // round-to-nearest-even
    return (unsigned short)(u >> 16);
}

__device__ __forceinline__ float bf2f(unsigned short s) {
    return __uint_as_float(((unsigned)s) << 16);
}

// R7 lesson: A&S-polynomial gelu with a (non-fast-math) IEEE divide + __expf is SLOWER
// than libm erff (VALUBusy 43->56%). Held at erff since R8 (one-lever discipline).
__device__ __forceinline__ float gelu_exact(float x) {
    return 0.5f * x * (1.0f + erff(x * 0.70710678118654752f));
}

// async global->LDS, 16B per lane; LDS dest = wave-uniform tile base (HW adds lane*16)
__device__ __forceinline__ void cp16(const unsigned short* g, unsigned short* l) {
    __builtin_amdgcn_global_load_lds(
        (const __attribute__((address_space(1))) unsigned int*)g,
        (__attribute__((address_space(3))) unsigned int*)l, 16, 0, 0);
}

// ------------------------- merged W1+W2 swizzle: fp32 [e][K][N] -> B-fragment bf16 tiles
// dst[((e*NT + nt)*KT + kt)*64 + l][j] = bf16(src[e][kt*16 + (l>>5)*8 + j][nt*32 + (l&31)])
// T1 = T2 = 589824 threads -> grid 4608x256 exactly. Block 0 zeroes cnt.
__global__ void swizzle_kernel(const float* __restrict__ W1, const float* __restrict__ W2,
                               unsigned short* __restrict__ w1s, unsigned short* __restrict__ w2s,
                               int* __restrict__ cnt) {
    if (blockIdx.x == 0 && threadIdx.x < NEXP) cnt[threadIdx.x] = 0;
    int gid = blockIdx.x * blockDim.x + threadIdx.x;
    const int T1 = NEXP * 48 * 24 * 64;        // 589824 threads for W1
    const int T2 = NEXP * 12 * 96 * 64;        // 589824 threads for W2
    const float* src; unsigned short* dst; int K, N, NT, KT, g;
    if (gid < T1)           { src = W1; dst = w1s; K = DIM; N = HID;  NT = 48; KT = 24; g = gid; }
    else if (gid < T1 + T2) { src = W2; dst = w2s; K = HID; N = OUTD; NT = 12; KT = 96; g = gid - T1; }
    else return;
    int l  = g & 63;
    int kt = (g >> 6) % KT;
    int nt = ((g >> 6) / KT) % NT;
    int e  = g / (64 * KT * NT);
    const float* s = src + ((size_t)e * K + kt * 16 + (l >> 5) * 8) * N + nt * 32 + (l & 31);
    unsigned short r[8];
    #pragma unroll
    for (int j = 0; j < 8; ++j) r[j] = f2bf(s[(size_t)j * N]);
    *(uint4*)(dst + (size_t)g * 8) = *(uint4*)r;
}

// ---------------------------------------------------------------- router
// 256 blocks x 256 thr: 32 tokens/block, 8 threads/token, coalesced 128B chunks;
// Wg staged transposed; __shfl_xor butterfly over seg bits. (R7: verified win.)
__global__ void router_kernel(const float* __restrict__ x, const float* __restrict__ Wg,
                              const float* __restrict__ bg, int* __restrict__ cnt,
                              int* __restrict__ btok, int* __restrict__ tokmap,
                              float* __restrict__ gmap) {
    __shared__ float WgL[NEXP * DIM];          // transposed: WgL[e*DIM + ch]
    __shared__ int lcnt[NEXP];
    __shared__ int lbase[NEXP];
    int tid = threadIdx.x;
    for (int i = tid; i < DIM * NEXP; i += 256) {
        int ch = i >> 3, e = i & 7;            // Wg row-major read = coalesced
        WgL[e * DIM + ch] = Wg[i];
    }
    if (tid < NEXP) lcnt[tid] = 0;
    __syncthreads();

    int tl  = tid >> 3;                        // token-in-block 0..31
    int seg = tid & 7;                         // channel segment 0..7 (lane bits 2:0)
    int t   = blockIdx.x * 32 + tl;

    float lg[NEXP] = {0.f, 0.f, 0.f, 0.f, 0.f, 0.f, 0.f, 0.f};
    const float* xr = x + (size_t)t * DIM;
    #pragma unroll
    for (int d4 = 0; d4 < 12; ++d4) {
        float4 v = *(const float4*)(xr + d4 * 32 + seg * 4);
        #pragma unroll
        for (int e = 0; e < NEXP; ++e) {
            float4 w = *(const float4*)&WgL[e * DIM + d4 * 32 + seg * 4];
            lg[e] += v.x * w.x + v.y * w.y + v.z * w.z + v.w * w.w;
        }
    }
    #pragma unroll
    for (int off = 1; off < 8; off <<= 1)
        #pragma unroll
        for (int e = 0; e < NEXP; ++e)
            lg[e] += __shfl_xor(lg[e], off);

    int p0 = 0, p1 = 0, i0 = 0, i1 = 0;
    float g0 = 0.f, g1 = 0.f;
    if (seg == 0) {
        float v0 = -INFINITY, v1 = -INFINITY;
        #pragma unroll
        for (int e = 0; e < NEXP; ++e) {
            float v = lg[e] + bg[e];
            if (v > v0)      { v1 = v0; i1 = i0; v0 = v; i0 = e; }
            else if (v > v1) { v1 = v;  i1 = e; }
        }
        float e1 = expf(v1 - v0);
        g0 = 1.f / (1.f + e1);
        g1 = e1  / (1.f + e1);
        p0 = atomicAdd(&lcnt[i0], 1);
        p1 = atomicAdd(&lcnt[i1], 1);
    }
    __syncthreads();
    if (tid < NEXP) lbase[tid] = atomicAdd(&cnt[tid], lcnt[tid]);
    __syncthreads();
    if (seg == 0) {
        int o0 = lbase[i0] + p0, o1 = lbase[i1] + p1;
        btok[i0 * N_TOK + o0] = t;
        btok[i1 * N_TOK + o1] = t;
        ((int4*)tokmap)[t] = make_int4(i0, o0, i1, o1);
        ((float2*)gmap)[t] = make_float2(g0, g1);
    }
}

// ------------------------------------------ gather x rows into A-fragment order (bf16)
__global__ void gather_kernel(const float* __restrict__ x, const int* __restrict__ cnt,
                              const int* __restrict__ btok, unsigned short* __restrict__ xg) {
    int mt = blockIdx.x, e = blockIdx.y;
    int cntE = cnt[e];
    if (mt * 32 >= cntE) return;
    int tid = threadIdx.x;                 // 256
    int m = tid & 31, kt0 = tid >> 5;      // 32 x 8
    int pos = mt * 32 + m;
    int idx = (pos < cntE) ? pos : cntE - 1;   // clamp pad rows (masked later)
    int tok = btok[e * N_TOK + idx];
    const float* xr = x + (size_t)tok * DIM;
    #pragma unroll
    for (int kk = 0; kk < 3; ++kk) {
        int kt = kt0 + kk * 8;
        #pragma unroll
        for (int kh = 0; kh < 2; ++kh) {
            float4 v0 = *(const float4*)(xr + kt * 16 + kh * 8);
            float4 v1 = *(const float4*)(xr + kt * 16 + kh * 8 + 4);
            unsigned short rr[8];
            rr[0] = f2bf(v0.x); rr[1] = f2bf(v0.y); rr[2] = f2bf(v0.z); rr[3] = f2bf(v0.w);
            rr[4] = f2bf(v1.x); rr[5] = f2bf(v1.y); rr[6] = f2bf(v1.z); rr[7] = f2bf(v1.w);
            *(uint4*)(xg + (size_t)(((e * CAP_MT + mt) * 24 + kt) * 64 + kh * 32 + m) * 8) =
                *(uint4*)rr;
        }
    }
}

// ---------------------------------------------------------------- GEMM1: h = gelu(xg@W1+b1)
// 2-phase prefetch double buffer (R12: verified, 45.4 -> 42.5 us): issue round ks+1
// into buf[(ks+1)&1] BEFORE consuming buf[ks&1], one barrier per round. BK=64,
// 2x32KB buffers, 8 waves, wave-tile 64x32.
__global__ __launch_bounds__(512, 4) void gemm1_kernel(
        const unsigned short* __restrict__ xg, const unsigned short* __restrict__ w1s,
        const float* __restrict__ b1, const int* __restrict__ cnt,
        unsigned short* __restrict__ h) {
    int L = blockIdx.x;                   // e in low 3 bits: XCD pin
    int e = L & 7;
    int r = L >> 3;
    int nb = r % 12;                      // 128-col slice of HID
    int tb = r / 12;                      // 128-token block
    int cntE = cnt[e];
    if (tb * 128 >= cntE) return;

    __shared__ unsigned short stg[2][16384];   // 2 x 32 KB; per buf: A [0..15], B [16..31]

    int tid = threadIdx.x;
    int wave = tid >> 6, lane = tid & 63;
    int m31 = lane & 31, kh = lane >> 5;
    int wm = wave & 1;                    // 64-row half
    int wn = wave >> 1;                   // 32-col quarter (0..3)

    f32x16 acc[2];
    acc[0] = (f32x16){0.f,0.f,0.f,0.f,0.f,0.f,0.f,0.f,0.f,0.f,0.f,0.f,0.f,0.f,0.f,0.f};
    acc[1] = acc[0];

    const unsigned short* xa = xg  + ((size_t)(e * CAP_MT + tb * 4) * 24) * 512;
    const unsigned short* wb = w1s + ((size_t)(e * 48 + nb * 4) * 24) * 512;

    // per-wave staging source base: waves 0-3 -> A (mt = wave), waves 4-7 -> B (nt).
    // Per round: 4 contiguous kt-tiles starting at ks*4.
    const unsigned short* sbase = (wave < 4)
        ? xa + ((size_t)wave * 24) * 512 + lane * 8
        : wb + ((size_t)(wave - 4) * 24) * 512 + lane * 8;
    int tbase = (wave < 4) ? wave * 4 : 16 + (wave - 4) * 4;   // tile slot in buf

    auto issue = [&](int ks) {
        unsigned short* dst = &stg[ks & 1][tbase * 512];
        const unsigned short* sk = sbase + (size_t)ks * 2048;  // 4 tiles x 512 shorts
        #pragma unroll
        for (int q = 0; q < 4; ++q)
            cp16(sk + q * 512, dst + q * 512);
    };

    issue(0);
    for (int ks = 0; ks < 6; ++ks) {            // K = 384 = 6 x BK64
        __syncthreads();                         // buf[ks&1] landed (implicit vmcnt(0)
                                                 // drain) + prev consume complete
        if (ks < 5) issue(ks + 1);               // prefetch flies under consume below
        const unsigned short* bufp = stg[ks & 1];
        #pragma unroll
        for (int kt = 0; kt < 4; ++kt) {
            bf16x8 b  = *(const bf16x8*)&bufp[(16 + wn * 4 + kt) * 512 + lane * 8];
            bf16x8 a0 = *(const bf16x8*)&bufp[((wm * 2 + 0) * 4 + kt) * 512 + lane * 8];
            bf16x8 a1 = *(const bf16x8*)&bufp[((wm * 2 + 1) * 4 + kt) * 512 + lane * 8];
            acc[0] = __builtin_amdgcn_mfma_f32_32x32x16_bf16(a0, b, acc[0], 0, 0, 0);
            acc[1] = __builtin_amdgcn_mfma_f32_32x32x16_bf16(a1, b, acc[1], 0, 0, 0);
        }
    }

    // ---- epilogue: bias + gelu -> per-wave 5 KB region (80B pitch), then h tiles ----
    __syncthreads();                             // all waves done reading stg
    char* hw = (char*)stg + wave * 5120;         // 64 rows x 80 B (40 KB <= 64 KB)
    float bv = b1[e * HID + nb * 128 + wn * 32 + m31];
    #pragma unroll
    for (int s = 0; s < 2; ++s)
        #pragma unroll
        for (int rr = 0; rr < 16; ++rr) {
            int rowl = s * 32 + (rr & 3) + 8 * (rr >> 2) + 4 * kh;   // 0..63 (token row)
            *(unsigned short*)(hw + rowl * 80 + m31 * 2) = f2bf(gelu_exact(acc[s][rr] + bv));
        }
    // read back as A-fragment tiles (lane l: row = l&31, k = (l>>5)*8 + j), store h.
    // wave-private region: compiler inserts the lgkmcnt for the RAW.
    #pragma unroll
    for (int mtl = 0; mtl < 2; ++mtl)
        #pragma unroll
        for (int ktl = 0; ktl < 2; ++ktl) {
            uint4 v = *(const uint4*)(hw + (mtl * 32 + m31) * 80 + (ktl * 16 + kh * 8) * 2);
            int mt = tb * 4 + wm * 2 + mtl;           // token tile (32 rows)
            int kt = nb * 8 + wn * 2 + ktl;           // hid tile (16 k)
            *(uint4*)(h + ((size_t)((e * CAP_MT + mt) * 96 + kt)) * 512 + lane * 8) = v;
        }
}

// ---------------------------------------------------------------- GEMM2: yp = h @ W2
// R13: same 2-phase prefetch double buffer as gemm1 (the R12-verified transfer).
// BK=64, 2x32KB buffers, 24 rounds (K=1536) — more rounds than gemm1, so the
// prefetch amortizes proportionally more. 8 waves, wave-tile 64x32. Full-K f32
// accumulation; epilogue transposes 64x32 per wave via 4 KB region (R10-verified).
__global__ __launch_bounds__(512, 4) void gemm2_kernel(
        const unsigned short* __restrict__ h, const unsigned short* __restrict__ w2s,
        const int* __restrict__ cnt, unsigned short* __restrict__ yp) {
    int L = blockIdx.x;
    int e = L & 7;
    int r = L >> 3;
    int nb = r % 3;                        // 128-col slice of OUTD
    int tb = r / 3;                        // 128-token block
    int cntE = cnt[e];
    if (tb * 128 >= cntE) return;

    __shared__ unsigned short stg[2][16384];   // 2 x 32 KB; per buf: A [0..15], B [16..31]

    int tid = threadIdx.x;
    int wave = tid >> 6, lane = tid & 63;
    int m31 = lane & 31, kh = lane >> 5;
    int wm = wave & 1;                     // 64-row half
    int wn = wave >> 1;                    // 32-col quarter (0..3)

    f32x16 acc[2];
    acc[0] = (f32x16){0.f,0.f,0.f,0.f,0.f,0.f,0.f,0.f,0.f,0.f,0.f,0.f,0.f,0.f,0.f,0.f};
    acc[1] = acc[0];

    const unsigned short* xa = h   + ((size_t)(e * CAP_MT + tb * 4) * 96) * 512;
    const unsigned short* wb = w2s + ((size_t)(e * 12 + nb * 4) * 96) * 512;

    const unsigned short* sbase = (wave < 4)
        ? xa + ((size_t)wave * 96) * 512 + lane * 8
        : wb + ((size_t)(wave - 4) * 96) * 512 + lane * 8;
    int tbase = (wave < 4) ? wave * 4 : 16 + (wave - 4) * 4;   // tile slot in buf

    auto issue = [&](int ks) {
        unsigned short* dst = &stg[ks & 1][tbase * 512];
        const unsigned short* sk = sbase + (size_t)ks * 2048;  // 4 kt-tiles x 512 shorts
        #pragma unroll
        for (int q = 0; q < 4; ++q)
            cp16(sk + q * 512, dst + q * 512);
    };

    issue(0);
    for (int ks = 0; ks < 24; ++ks) {          // K = 1536 = 24 x BK64
        __syncthreads();                        // buf[ks&1] landed + prev consume done
        if (ks < 23) issue(ks + 1);             // prefetch flies under consume below
        const unsigned short* bufp = stg[ks & 1];
        #pragma unroll
        for (int kt = 0; kt < 4; ++kt) {
            bf16x8 b  = *(const bf16x8*)&bufp[(16 + wn * 4 + kt) * 512 + lane * 8];
            bf16x8 a0 = *(const bf16x8*)&bufp[((wm * 2 + 0) * 4 + kt) * 512 + lane * 8];
            bf16x8 a1 = *(const bf16x8*)&bufp[((wm * 2 + 1) * 4 + kt) * 512 + lane * 8];
            acc[0] = __builtin_amdgcn_mfma_f32_32x32x16_bf16(a0, b, acc[0], 0, 0, 0);
            acc[1] = __builtin_amdgcn_mfma_f32_32x32x16_bf16(a1, b, acc[1], 0, 0, 0);
        }
    }

    // ---- epilogue: per-wave 4 KB region (64 rows x 64 B) ----
    __syncthreads();                           // all waves done with stage reads
    char* hw = (char*)stg + wave * 4096;       // 64 rows x 64 B = 4096 B per wave
    #pragma unroll
    for (int s = 0; s < 2; ++s)
        #pragma unroll
        for (int rr = 0; rr < 16; ++rr) {
            int rowl = s * 32 + (rr & 3) + 8 * (rr >> 2) + 4 * kh;   // 0..63
            *(unsigned short*)(hw + rowl * 64 + m31 * 2) = f2bf(acc[s][rr]);
        }
    // read-back: addr = it*1024 + lane*16 (4-way max); store row-major
    #pragma unroll
    for (int it = 0; it < 4; ++it) {
        int rowl = it * 16 + (lane >> 2);
        int cc   = lane & 3;
        uint4 v = *(const uint4*)(hw + rowl * 64 + cc * 16);
        int pos = tb * 128 + wm * 64 + rowl;
        *(uint4*)(yp + (size_t)(e * CAP_TOK + pos) * OUTD + nb * 128 + wn * 32 + cc * 8) = v;
    }
}

// ----------- reduce: out = sum_k g_k * (yp[e_k][pos_k] + b2[e_k]); single full-K partial
__global__ void reduce_kernel(const unsigned short* __restrict__ yp,
                              const int* __restrict__ tokmap, const float* __restrict__ gmap,
                              const float* __restrict__ b2, float* __restrict__ out) {
    int gid = blockIdx.x * 256 + threadIdx.x;      // N_TOK * 48 threads
    int t = gid / 48, q = gid - t * 48;            // q: 8-col group
    int4   tm = ((const int4*)tokmap)[t];
    float2 g  = ((const float2*)gmap)[t];
    const unsigned short* p0 = yp + ((size_t)(tm.x * CAP_TOK + tm.y)) * OUTD + q * 8;
    const unsigned short* p1 = yp + ((size_t)(tm.z * CAP_TOK + tm.w)) * OUTD + q * 8;
    u16x8 a = __builtin_nontemporal_load((const u16x8*)p0);
    u16x8 b = __builtin_nontemporal_load((const u16x8*)p1);
    const float* c0 = &b2[tm.x * OUTD + q * 8];
    const float* c1 = &b2[tm.z * OUTD + q * 8];
    f32x4 r0, r1;
    #pragma unroll
    for (int j = 0; j < 4; ++j) {
        r0[j] = g.x * (bf2f(a[j]) + c0[j]) + g.y * (bf2f(b[j]) + c1[j]);
        r1[j] = g.x * (bf2f(a[4 + j]) + c0[4 + j]) + g.y * (bf2f(b[4 + j]) + c1[4 + j]);
    }
    float* op = &out[(size_t)t * OUTD + q * 8];
    __builtin_nontemporal_store(r0, (f32x4*)op);
    __builtin_nontemporal_store(r1, (f32x4*)(op + 4));
}

// ---------------------------------------------------------------- launch
extern "C" void kernel_launch(void* const* d_in, const int* in_sizes, int n_in,
                              void* d_out, int out_size, void* d_ws, size_t ws_size,
                              hipStream_t stream) {
    const float* x  = (const float*)d_in[0];
    const float* Wg = (const float*)d_in[1];
    const float* bg = (const float*)d_in[2];
    const float* W1 = (const float*)d_in[3];
    const float* b1 = (const float*)d_in[4];
    const float* W2 = (const float*)d_in[5];
    const float* b2 = (const float*)d_in[6];
    float* out = (float*)d_out;

    char* ws = (char*)d_ws;                                    // all offsets 1KB-aligned
    int*            cnt    = (int*)ws;                         // 32 B
    int*            btok   = (int*)(ws + 1024);                // 256 KB
    int*            tokmap = (int*)(ws + 263168);              // 128 KB
    float*          gmap   = (float*)(ws + 394240);            // 64 KB
    unsigned short* xg     = (unsigned short*)(ws + 459776);   // 13.5 MB (tiles 8x72x24)
    unsigned short* w1s    = (unsigned short*)(ws + 14615552); // 9.44 MB
    unsigned short* w2s    = (unsigned short*)(ws + 24052736); // 9.44 MB
    unsigned short* h      = (unsigned short*)(ws + 33489920); // 56.6 MB (tiles 8x72x96)
    // yp (8 x 2304 x 384 bf16 = 13.5 MB) aliases the xg slot: gemm2 runs strictly after
    // gemm1's last read of xg (same stream), and next iteration's gather fully rewrites
    // the tiles gemm1 reads. Keeps workspace footprint identical.
    unsigned short* yp     = xg;

    // merged W1+W2 swizzle: (589824 + 589824) / 256 = 4608 blocks exactly
    hipLaunchKernelGGL(swizzle_kernel, dim3(4608), dim3(256), 0, stream,
                       W1, W2, w1s, w2s, cnt);
    hipLaunchKernelGGL(router_kernel, dim3(N_TOK / 32), dim3(256), 0, stream,
                       x, Wg, bg, cnt, btok, tokmap, gmap);
    hipLaunchKernelGGL(gather_kernel, dim3(CAP_MT, NEXP), dim3(256), 0, stream,
                       x, cnt, btok, xg);
    hipLaunchKernelGGL(gemm1_kernel, dim3(NEXP * 12 * CAP_TB), dim3(512), 0, stream,
                       xg, w1s, b1, cnt, h);
    hipLaunchKernelGGL(gemm2_kernel, dim3(NEXP * 3 * CAP_TB), dim3(512), 0, stream,
                       h, w2s, cnt, yp);
    hipLaunchKernelGGL(reduce_kernel, dim3(N_TOK * 48 / 256), dim3(256), 0, stream,
                       yp, tokmap, gmap, b2, out);
}

// Round 14
// 183.843 us; speedup vs baseline: 1.0147x; 1.0147x over previous
//
#include <hip/hip_runtime.h>
#include <cmath>

#define N_TOK 8192
#define DIM   384
#define NEXP  8
#define HID   1536
#define OUTD  384
#define CAP_MT 72        // 32-row gather tiles per expert (2304 tokens, mean 2048 + 6 sigma)
#define CAP_TOK 2304
#define CAP_TB 18        // 128-row blocks per expert

typedef __attribute__((ext_vector_type(8)))  __bf16 bf16x8;
typedef __attribute__((ext_vector_type(16))) float  f32x16;
typedef __attribute__((ext_vector_type(4)))  float  f32x4;          // nontemporal builtins
typedef __attribute__((ext_vector_type(8)))  unsigned short u16x8;  // nontemporal bf16 loads

__device__ __forceinline__ unsigned short f2bf(float f) {
    unsigned u = __float_as_uint(f);
    u += 0x7FFF + ((u >> 16) & 1);          // round-to-nearest-even
    return (unsigned short)(u >> 16);
}

__device__ __forceinline__ float bf2f(unsigned short s) {
    return __uint_as_float(((unsigned)s) << 16);
}

// R7 lesson: A&S-polynomial gelu with a (non-fast-math) IEEE divide + __expf is SLOWER
// than libm erff (VALUBusy 43->56%). Held at erff since R8 (one-lever discipline).
__device__ __forceinline__ float gelu_exact(float x) {
    return 0.5f * x * (1.0f + erff(x * 0.70710678118654752f));
}

// async global->LDS, 16B per lane; LDS dest = wave-uniform tile base (HW adds lane*16)
__device__ __forceinline__ void cp16(const unsigned short* g, unsigned short* l) {
    __builtin_amdgcn_global_load_lds(
        (const __attribute__((address_space(1))) unsigned int*)g,
        (__attribute__((address_space(3))) unsigned int*)l, 16, 0, 0);
}

// ------------------------- merged W1+W2 swizzle: fp32 [e][K][N] -> B-fragment bf16 tiles
// dst[((e*NT + nt)*KT + kt)*64 + l][j] = bf16(src[e][kt*16 + (l>>5)*8 + j][nt*32 + (l&31)])
// T1 = T2 = 589824 threads -> grid 4608x256 exactly. Block 0 zeroes cnt.
__global__ void swizzle_kernel(const float* __restrict__ W1, const float* __restrict__ W2,
                               unsigned short* __restrict__ w1s, unsigned short* __restrict__ w2s,
                               int* __restrict__ cnt) {
    if (blockIdx.x == 0 && threadIdx.x < NEXP) cnt[threadIdx.x] = 0;
    int gid = blockIdx.x * blockDim.x + threadIdx.x;
    const int T1 = NEXP * 48 * 24 * 64;        // 589824 threads for W1
    const int T2 = NEXP * 12 * 96 * 64;        // 589824 threads for W2
    const float* src; unsigned short* dst; int K, N, NT, KT, g;
    if (gid < T1)           { src = W1; dst = w1s; K = DIM; N = HID;  NT = 48; KT = 24; g = gid; }
    else if (gid < T1 + T2) { src = W2; dst = w2s; K = HID; N = OUTD; NT = 12; KT = 96; g = gid - T1; }
    else return;
    int l  = g & 63;
    int kt = (g >> 6) % KT;
    int nt = ((g >> 6) / KT) % NT;
    int e  = g / (64 * KT * NT);
    const float* s = src + ((size_t)e * K + kt * 16 + (l >> 5) * 8) * N + nt * 32 + (l & 31);
    unsigned short r[8];
    #pragma unroll
    for (int j = 0; j < 8; ++j) r[j] = f2bf(s[(size_t)j * N]);
    *(uint4*)(dst + (size_t)g * 8) = *(uint4*)r;
}

// ---------------------------------------------------------------- router
// 256 blocks x 256 thr: 32 tokens/block, 8 threads/token, coalesced 128B chunks;
// Wg staged transposed; __shfl_xor butterfly over seg bits. (R7: verified win.)
__global__ void router_kernel(const float* __restrict__ x, const float* __restrict__ Wg,
                              const float* __restrict__ bg, int* __restrict__ cnt,
                              int* __restrict__ btok, int* __restrict__ tokmap,
                              float* __restrict__ gmap) {
    __shared__ float WgL[NEXP * DIM];          // transposed: WgL[e*DIM + ch]
    __shared__ int lcnt[NEXP];
    __shared__ int lbase[NEXP];
    int tid = threadIdx.x;
    for (int i = tid; i < DIM * NEXP; i += 256) {
        int ch = i >> 3, e = i & 7;            // Wg row-major read = coalesced
        WgL[e * DIM + ch] = Wg[i];
    }
    if (tid < NEXP) lcnt[tid] = 0;
    __syncthreads();

    int tl  = tid >> 3;                        // token-in-block 0..31
    int seg = tid & 7;                         // channel segment 0..7 (lane bits 2:0)
    int t   = blockIdx.x * 32 + tl;

    float lg[NEXP] = {0.f, 0.f, 0.f, 0.f, 0.f, 0.f, 0.f, 0.f};
    const float* xr = x + (size_t)t * DIM;
    #pragma unroll
    for (int d4 = 0; d4 < 12; ++d4) {
        float4 v = *(const float4*)(xr + d4 * 32 + seg * 4);
        #pragma unroll
        for (int e = 0; e < NEXP; ++e) {
            float4 w = *(const float4*)&WgL[e * DIM + d4 * 32 + seg * 4];
            lg[e] += v.x * w.x + v.y * w.y + v.z * w.z + v.w * w.w;
        }
    }
    #pragma unroll
    for (int off = 1; off < 8; off <<= 1)
        #pragma unroll
        for (int e = 0; e < NEXP; ++e)
            lg[e] += __shfl_xor(lg[e], off);

    int p0 = 0, p1 = 0, i0 = 0, i1 = 0;
    float g0 = 0.f, g1 = 0.f;
    if (seg == 0) {
        float v0 = -INFINITY, v1 = -INFINITY;
        #pragma unroll
        for (int e = 0; e < NEXP; ++e) {
            float v = lg[e] + bg[e];
            if (v > v0)      { v1 = v0; i1 = i0; v0 = v; i0 = e; }
            else if (v > v1) { v1 = v;  i1 = e; }
        }
        float e1 = expf(v1 - v0);
        g0 = 1.f / (1.f + e1);
        g1 = e1  / (1.f + e1);
        p0 = atomicAdd(&lcnt[i0], 1);
        p1 = atomicAdd(&lcnt[i1], 1);
    }
    __syncthreads();
    if (tid < NEXP) lbase[tid] = atomicAdd(&cnt[tid], lcnt[tid]);
    __syncthreads();
    if (seg == 0) {
        int o0 = lbase[i0] + p0, o1 = lbase[i1] + p1;
        btok[i0 * N_TOK + o0] = t;
        btok[i1 * N_TOK + o1] = t;
        ((int4*)tokmap)[t] = make_int4(i0, o0, i1, o1);
        ((float2*)gmap)[t] = make_float2(g0, g1);
    }
}

// ------------------------------------------ gather x rows into A-fragment order (bf16)
__global__ void gather_kernel(const float* __restrict__ x, const int* __restrict__ cnt,
                              const int* __restrict__ btok, unsigned short* __restrict__ xg) {
    int mt = blockIdx.x, e = blockIdx.y;
    int cntE = cnt[e];
    if (mt * 32 >= cntE) return;
    int tid = threadIdx.x;                 // 256
    int m = tid & 31, kt0 = tid >> 5;      // 32 x 8
    int pos = mt * 32 + m;
    int idx = (pos < cntE) ? pos : cntE - 1;   // clamp pad rows (masked later)
    int tok = btok[e * N_TOK + idx];
    const float* xr = x + (size_t)tok * DIM;
    #pragma unroll
    for (int kk = 0; kk < 3; ++kk) {
        int kt = kt0 + kk * 8;
        #pragma unroll
        for (int kh = 0; kh < 2; ++kh) {
            float4 v0 = *(const float4*)(xr + kt * 16 + kh * 8);
            float4 v1 = *(const float4*)(xr + kt * 16 + kh * 8 + 4);
            unsigned short rr[8];
            rr[0] = f2bf(v0.x); rr[1] = f2bf(v0.y); rr[2] = f2bf(v0.z); rr[3] = f2bf(v0.w);
            rr[4] = f2bf(v1.x); rr[5] = f2bf(v1.y); rr[6] = f2bf(v1.z); rr[7] = f2bf(v1.w);
            *(uint4*)(xg + (size_t)(((e * CAP_MT + mt) * 24 + kt) * 64 + kh * 32 + m) * 8) =
                *(uint4*)rr;
        }
    }
}

// ---------------------------------------------------------------- GEMM1: h = gelu(xg@W1+b1)
// R14: T4 counted-vmcnt depth-2 pipeline. BK=48 (24KB round, exactly 3 cp16/wave),
// 3 buffers (72KB -> still 2 blocks/CU). Main loop: s_waitcnt vmcnt(3) (round ks
// landed, round ks+1's 3 loads STAY IN FLIGHT across the raw s_barrier — the thing
// __syncthreads' implicit drain forbids, and the reason R12/R13's drain-0 prefetch
// was ~null per m218: counted-vs-drain0 is the whole gain) -> s_barrier ->
// issue(ks+2) -> consume(ks). Rotation safe: barrier(ks) follows consume(ks-1), so
// issue(ks+2) into buf[(ks+2)%3]==buf[(ks-1)%3] can't race. Last round peeled with
// vmcnt(0). 8 waves, wave-tile 64x32.
__global__ __launch_bounds__(512, 4) void gemm1_kernel(
        const unsigned short* __restrict__ xg, const unsigned short* __restrict__ w1s,
        const float* __restrict__ b1, const int* __restrict__ cnt,
        unsigned short* __restrict__ h) {
    int L = blockIdx.x;                   // e in low 3 bits: XCD pin
    int e = L & 7;
    int r = L >> 3;
    int nb = r % 12;                      // 128-col slice of HID
    int tb = r / 12;                      // 128-token block
    int cntE = cnt[e];
    if (tb * 128 >= cntE) return;

    __shared__ unsigned short stg[3][12288];   // 3 x 24 KB; per buf: A [0..11], B [12..23]

    int tid = threadIdx.x;
    int wave = tid >> 6, lane = tid & 63;
    int m31 = lane & 31, kh = lane >> 5;
    int wm = wave & 1;                    // 64-row half
    int wn = wave >> 1;                   // 32-col quarter (0..3)

    f32x16 acc[2];
    acc[0] = (f32x16){0.f,0.f,0.f,0.f,0.f,0.f,0.f,0.f,0.f,0.f,0.f,0.f,0.f,0.f,0.f,0.f};
    acc[1] = acc[0];

    const unsigned short* xa = xg  + ((size_t)(e * CAP_MT + tb * 4) * 24) * 512;
    const unsigned short* wb = w1s + ((size_t)(e * 48 + nb * 4) * 24) * 512;

    // per-wave source base: waves 0-3 -> A (mt = wave), waves 4-7 -> B (nt = wave-4).
    // Round ks covers global kt = ks*3 + q, q=0..2 (tile stride 512 shorts).
    const unsigned short* sbase = (wave < 4)
        ? xa + ((size_t)wave * 24) * 512 + lane * 8
        : wb + ((size_t)(wave - 4) * 24) * 512 + lane * 8;
    int tbase = (wave < 4) ? wave * 3 : 12 + (wave - 4) * 3;   // tile slot in buf

    auto issue = [&](int ks) {
        unsigned short* dst = &stg[ks % 3][tbase * 512];
        const unsigned short* sk = sbase + (size_t)ks * 1536;  // 3 kt-tiles x 512
        #pragma unroll
        for (int q = 0; q < 3; ++q)
            cp16(sk + q * 512, dst + q * 512);
    };
    auto consume = [&](int ks) {
        const unsigned short* bufp = stg[ks % 3];
        #pragma unroll
        for (int kt = 0; kt < 3; ++kt) {
            bf16x8 b  = *(const bf16x8*)&bufp[(12 + wn * 3 + kt) * 512 + lane * 8];
            bf16x8 a0 = *(const bf16x8*)&bufp[((wm * 2 + 0) * 3 + kt) * 512 + lane * 8];
            bf16x8 a1 = *(const bf16x8*)&bufp[((wm * 2 + 1) * 3 + kt) * 512 + lane * 8];
            acc[0] = __builtin_amdgcn_mfma_f32_32x32x16_bf16(a0, b, acc[0], 0, 0, 0);
            acc[1] = __builtin_amdgcn_mfma_f32_32x32x16_bf16(a1, b, acc[1], 0, 0, 0);
        }
    };

    issue(0); issue(1);                          // prologue: 6 loads in flight
    for (int ks = 0; ks < 7; ++ks) {             // K = 384 = 8 x BK48; rounds 0..6
        asm volatile("s_waitcnt vmcnt(3) lgkmcnt(0)" ::: "memory");  // round ks landed
        __builtin_amdgcn_sched_barrier(0);
        __builtin_amdgcn_s_barrier();            // raw: ks+1's loads NOT drained
        __builtin_amdgcn_sched_barrier(0);
        if (ks + 2 < 8) issue(ks + 2);
        consume(ks);
    }
    // peeled final round 7: only its 3 loads outstanding -> full drain
    asm volatile("s_waitcnt vmcnt(0) lgkmcnt(0)" ::: "memory");
    __builtin_amdgcn_sched_barrier(0);
    __builtin_amdgcn_s_barrier();
    __builtin_amdgcn_sched_barrier(0);
    consume(7);

    // ---- epilogue: bias + gelu -> per-wave 5 KB region (80B pitch), then h tiles ----
    __syncthreads();                             // all waves done reading stg
    char* hw = (char*)stg + wave * 5120;         // 64 rows x 80 B (40 KB <= 72 KB)
    float bv = b1[e * HID + nb * 128 + wn * 32 + m31];
    #pragma unroll
    for (int s = 0; s < 2; ++s)
        #pragma unroll
        for (int rr = 0; rr < 16; ++rr) {
            int rowl = s * 32 + (rr & 3) + 8 * (rr >> 2) + 4 * kh;   // 0..63 (token row)
            *(unsigned short*)(hw + rowl * 80 + m31 * 2) = f2bf(gelu_exact(acc[s][rr] + bv));
        }
    // read back as A-fragment tiles (lane l: row = l&31, k = (l>>5)*8 + j), store h.
    // wave-private region: compiler inserts the lgkmcnt for the RAW.
    #pragma unroll
    for (int mtl = 0; mtl < 2; ++mtl)
        #pragma unroll
        for (int ktl = 0; ktl < 2; ++ktl) {
            uint4 v = *(const uint4*)(hw + (mtl * 32 + m31) * 80 + (ktl * 16 + kh * 8) * 2);
            int mt = tb * 4 + wm * 2 + mtl;           // token tile (32 rows)
            int kt = nb * 8 + wn * 2 + ktl;           // hid tile (16 k)
            *(uint4*)(h + ((size_t)((e * CAP_MT + mt) * 96 + kt)) * 512 + lane * 8) = v;
        }
}

// ---------------------------------------------------------------- GEMM2: yp = h @ W2
// R14: same T4 counted-vmcnt depth-2 structure (BK=48, 32 rounds for K=1536,
// 3 x 24KB buffers). Full-K f32 accumulation; epilogue transposes 64x32 per wave
// via 4 KB region (R10-verified, wave*4096 stride).
__global__ __launch_bounds__(512, 4) void gemm2_kernel(
        const unsigned short* __restrict__ h, const unsigned short* __restrict__ w2s,
        const int* __restrict__ cnt, unsigned short* __restrict__ yp) {
    int L = blockIdx.x;
    int e = L & 7;
    int r = L >> 3;
    int nb = r % 3;                        // 128-col slice of OUTD
    int tb = r / 3;                        // 128-token block
    int cntE = cnt[e];
    if (tb * 128 >= cntE) return;

    __shared__ unsigned short stg[3][12288];   // 3 x 24 KB; per buf: A [0..11], B [12..23]

    int tid = threadIdx.x;
    int wave = tid >> 6, lane = tid & 63;
    int m31 = lane & 31, kh = lane >> 5;
    int wm = wave & 1;                     // 64-row half
    int wn = wave >> 1;                    // 32-col quarter (0..3)

    f32x16 acc[2];
    acc[0] = (f32x16){0.f,0.f,0.f,0.f,0.f,0.f,0.f,0.f,0.f,0.f,0.f,0.f,0.f,0.f,0.f,0.f};
    acc[1] = acc[0];

    const unsigned short* xa = h   + ((size_t)(e * CAP_MT + tb * 4) * 96) * 512;
    const unsigned short* wb = w2s + ((size_t)(e * 12 + nb * 4) * 96) * 512;

    const unsigned short* sbase = (wave < 4)
        ? xa + ((size_t)wave * 96) * 512 + lane * 8
        : wb + ((size_t)(wave - 4) * 96) * 512 + lane * 8;
    int tbase = (wave < 4) ? wave * 3 : 12 + (wave - 4) * 3;   // tile slot in buf

    auto issue = [&](int ks) {
        unsigned short* dst = &stg[ks % 3][tbase * 512];
        const unsigned short* sk = sbase + (size_t)ks * 1536;  // 3 kt-tiles x 512
        #pragma unroll
        for (int q = 0; q < 3; ++q)
            cp16(sk + q * 512, dst + q * 512);
    };
    auto consume = [&](int ks) {
        const unsigned short* bufp = stg[ks % 3];
        #pragma unroll
        for (int kt = 0; kt < 3; ++kt) {
            bf16x8 b  = *(const bf16x8*)&bufp[(12 + wn * 3 + kt) * 512 + lane * 8];
            bf16x8 a0 = *(const bf16x8*)&bufp[((wm * 2 + 0) * 3 + kt) * 512 + lane * 8];
            bf16x8 a1 = *(const bf16x8*)&bufp[((wm * 2 + 1) * 3 + kt) * 512 + lane * 8];
            acc[0] = __builtin_amdgcn_mfma_f32_32x32x16_bf16(a0, b, acc[0], 0, 0, 0);
            acc[1] = __builtin_amdgcn_mfma_f32_32x32x16_bf16(a1, b, acc[1], 0, 0, 0);
        }
    };

    issue(0); issue(1);
    for (int ks = 0; ks < 31; ++ks) {          // K = 1536 = 32 x BK48; rounds 0..30
        asm volatile("s_waitcnt vmcnt(3) lgkmcnt(0)" ::: "memory");
        __builtin_amdgcn_sched_barrier(0);
        __builtin_amdgcn_s_barrier();
        __builtin_amdgcn_sched_barrier(0);
        if (ks + 2 < 32) issue(ks + 2);
        consume(ks);
    }
    asm volatile("s_waitcnt vmcnt(0) lgkmcnt(0)" ::: "memory");
    __builtin_amdgcn_sched_barrier(0);
    __builtin_amdgcn_s_barrier();
    __builtin_amdgcn_sched_barrier(0);
    consume(31);

    // ---- epilogue: per-wave 4 KB region (64 rows x 64 B) ----
    __syncthreads();                           // all waves done with stage reads
    char* hw = (char*)stg + wave * 4096;       // 64 rows x 64 B = 4096 B per wave
    #pragma unroll
    for (int s = 0; s < 2; ++s)
        #pragma unroll
        for (int rr = 0; rr < 16; ++rr) {
            int rowl = s * 32 + (rr & 3) + 8 * (rr >> 2) + 4 * kh;   // 0..63
            *(unsigned short*)(hw + rowl * 64 + m31 * 2) = f2bf(acc[s][rr]);
        }
    // read-back: addr = it*1024 + lane*16 (4-way max); store row-major
    #pragma unroll
    for (int it = 0; it < 4; ++it) {
        int rowl = it * 16 + (lane >> 2);
        int cc   = lane & 3;
        uint4 v = *(const uint4*)(hw + rowl * 64 + cc * 16);
        int pos = tb * 128 + wm * 64 + rowl;
        *(uint4*)(yp + (size_t)(e * CAP_TOK + pos) * OUTD + nb * 128 + wn * 32 + cc * 8) = v;
    }
}

// ----------- reduce: out = sum_k g_k * (yp[e_k][pos_k] + b2[e_k]); single full-K partial
__global__ void reduce_kernel(const unsigned short* __restrict__ yp,
                              const int* __restrict__ tokmap, const float* __restrict__ gmap,
                              const float* __restrict__ b2, float* __restrict__ out) {
    int gid = blockIdx.x * 256 + threadIdx.x;      // N_TOK * 48 threads
    int t = gid / 48, q = gid - t * 48;            // q: 8-col group
    int4   tm = ((const int4*)tokmap)[t];
    float2 g  = ((const float2*)gmap)[t];
    const unsigned short* p0 = yp + ((size_t)(tm.x * CAP_TOK + tm.y)) * OUTD + q * 8;
    const unsigned short* p1 = yp + ((size_t)(tm.z * CAP_TOK + tm.w)) * OUTD + q * 8;
    u16x8 a = __builtin_nontemporal_load((const u16x8*)p0);
    u16x8 b = __builtin_nontemporal_load((const u16x8*)p1);
    const float* c0 = &b2[tm.x * OUTD + q * 8];
    const float* c1 = &b2[tm.z * OUTD + q * 8];
    f32x4 r0, r1;
    #pragma unroll
    for (int j = 0; j < 4; ++j) {
        r0[j] = g.x * (bf2f(a[j]) + c0[j]) + g.y * (bf2f(b[j]) + c1[j]);
        r1[j] = g.x * (bf2f(a[4 + j]) + c0[4 + j]) + g.y * (bf2f(b[4 + j]) + c1[4 + j]);
    }
    float* op = &out[(size_t)t * OUTD + q * 8];
    __builtin_nontemporal_store(r0, (f32x4*)op);
    __builtin_nontemporal_store(r1, (f32x4*)(op + 4));
}

// ---------------------------------------------------------------- launch
extern "C" void kernel_launch(void* const* d_in, const int* in_sizes, int n_in,
                              void* d_out, int out_size, void* d_ws, size_t ws_size,
                              hipStream_t stream) {
    const float* x  = (const float*)d_in[0];
    const float* Wg = (const float*)d_in[1];
    const float* bg = (const float*)d_in[2];
    const float* W1 = (const float*)d_in[3];
    const float* b1 = (const float*)d_in[4];
    const float* W2 = (const float*)d_in[5];
    const float* b2 = (const float*)d_in[6];
    float* out = (float*)d_out;

    char* ws = (char*)d_ws;                                    // all offsets 1KB-aligned
    int*            cnt    = (int*)ws;                         // 32 B
    int*            btok   = (int*)(ws + 1024);                // 256 KB
    int*            tokmap = (int*)(ws + 263168);              // 128 KB
    float*          gmap   = (float*)(ws + 394240);            // 64 KB
    unsigned short* xg     = (unsigned short*)(ws + 459776);   // 13.5 MB (tiles 8x72x24)
    unsigned short* w1s    = (unsigned short*)(ws + 14615552); // 9.44 MB
    unsigned short* w2s    = (unsigned short*)(ws + 24052736); // 9.44 MB
    unsigned short* h      = (unsigned short*)(ws + 33489920); // 56.6 MB (tiles 8x72x96)
    // yp (8 x 2304 x 384 bf16 = 13.5 MB) aliases the xg slot: gemm2 runs strictly after
    // gemm1's last read of xg (same stream), and next iteration's gather fully rewrites
    // the tiles gemm1 reads. Keeps workspace footprint identical.
    unsigned short* yp     = xg;

    // merged W1+W2 swizzle: (589824 + 589824) / 256 = 4608 blocks exactly
    hipLaunchKernelGGL(swizzle_kernel, dim3(4608), dim3(256), 0, stream,
                       W1, W2, w1s, w2s, cnt);
    hipLaunchKernelGGL(router_kernel, dim3(N_TOK / 32), dim3(256), 0, stream,
                       x, Wg, bg, cnt, btok, tokmap, gmap);
    hipLaunchKernelGGL(gather_kernel, dim3(CAP_MT, NEXP), dim3(256), 0, stream,
                       x, cnt, btok, xg);
    hipLaunchKernelGGL(gemm1_kernel, dim3(NEXP * 12 * CAP_TB), dim3(512), 0, stream,
                       xg, w1s, b1, cnt, h);
    hipLaunchKernelGGL(gemm2_kernel, dim3(NEXP * 3 * CAP_TB), dim3(512), 0, stream,
                       h, w2s, cnt, yp);
    hipLaunchKernelGGL(reduce_kernel, dim3(N_TOK * 48 / 256), dim3(256), 0, stream,
                       yp, tokmap, gmap, b2, out);
}

// Round 15
// 183.458 us; speedup vs baseline: 1.0168x; 1.0021x over previous
//
#include <hip/hip_runtime.h>
#include <cmath>

#define N_TOK 8192
#define DIM   384
#define NEXP  8
#define HID   1536
#define OUTD  384
#define CAP_TOK 2304
#define CAP_TB 18        // 128-row blocks per expert

typedef __attribute__((ext_vector_type(8)))  __bf16 bf16x8;
typedef __attribute__((ext_vector_type(16))) float  f32x16;
typedef __attribute__((ext_vector_type(4)))  float  f32x4;          // nontemporal builtins
typedef __attribute__((ext_vector_type(8)))  unsigned short u16x8;  // nontemporal bf16 loads

__device__ __forceinline__ unsigned short f2bf(float f) {
    unsigned u = __float_as_uint(f);
    u += 0x7FFF + ((u >> 16) & 1);          // round-to-nearest-even
    return (unsigned short)(u >> 16);
}

__device__ __forceinline__ float bf2f(unsigned short s) {
    return __uint_as_float(((unsigned)s) << 16);
}

// R7 lesson: A&S-polynomial gelu with a (non-fast-math) IEEE divide + __expf is SLOWER
// than libm erff (VALUBusy 43->56%). Held at erff since R8 (one-lever discipline).
__device__ __forceinline__ float gelu_exact(float x) {
    return 0.5f * x * (1.0f + erff(x * 0.70710678118654752f));
}

// async global->LDS, 16B per lane; LDS dest = wave-uniform tile base (HW adds lane*16).
// NOTE (m104): the GLOBAL source address is per-lane — R15 exploits this to fuse the
// gather permutation into gemm1's A-staging.
__device__ __forceinline__ void cp16(const unsigned short* g, unsigned short* l) {
    __builtin_amdgcn_global_load_lds(
        (const __attribute__((address_space(1))) unsigned int*)g,
        (__attribute__((address_space(3))) unsigned int*)l, 16, 0, 0);
}

// ------------------------- merged W1+W2 swizzle: fp32 [e][K][N] -> B-fragment bf16 tiles
// dst[((e*NT + nt)*KT + kt)*64 + l][j] = bf16(src[e][kt*16 + (l>>5)*8 + j][nt*32 + (l&31)])
// T1 = T2 = 589824 threads -> grid 4608x256 exactly. Block 0 zeroes cnt.
__global__ void swizzle_kernel(const float* __restrict__ W1, const float* __restrict__ W2,
                               unsigned short* __restrict__ w1s, unsigned short* __restrict__ w2s,
                               int* __restrict__ cnt) {
    if (blockIdx.x == 0 && threadIdx.x < NEXP) cnt[threadIdx.x] = 0;
    int gid = blockIdx.x * blockDim.x + threadIdx.x;
    const int T1 = NEXP * 48 * 24 * 64;        // 589824 threads for W1
    const int T2 = NEXP * 12 * 96 * 64;        // 589824 threads for W2
    const float* src; unsigned short* dst; int K, N, NT, KT, g;
    if (gid < T1)           { src = W1; dst = w1s; K = DIM; N = HID;  NT = 48; KT = 24; g = gid; }
    else if (gid < T1 + T2) { src = W2; dst = w2s; K = HID; N = OUTD; NT = 12; KT = 96; g = gid - T1; }
    else return;
    int l  = g & 63;
    int kt = (g >> 6) % KT;
    int nt = ((g >> 6) / KT) % NT;
    int e  = g / (64 * KT * NT);
    const float* s = src + ((size_t)e * K + kt * 16 + (l >> 5) * 8) * N + nt * 32 + (l & 31);
    unsigned short r[8];
    #pragma unroll
    for (int j = 0; j < 8; ++j) r[j] = f2bf(s[(size_t)j * N]);
    *(uint4*)(dst + (size_t)g * 8) = *(uint4*)r;
}

// ---------------------------------------------------------------- router (+ xb emit)
// 256 blocks x 256 thr: 32 tokens/block, 8 threads/token, coalesced 128B chunks;
// Wg staged transposed; __shfl_xor butterfly over seg bits. (R7: verified win.)
// R15: each thread also emits its token's channel segment as bf16 into xb[t][d]
// (row-major, 6.3 MB) — the input for gemm1's fused gather-staging. 8B stores,
// consecutive segs -> coalesced 64B per (token, d4).
__global__ void router_kernel(const float* __restrict__ x, const float* __restrict__ Wg,
                              const float* __restrict__ bg, int* __restrict__ cnt,
                              int* __restrict__ btok, int* __restrict__ tokmap,
                              float* __restrict__ gmap, unsigned short* __restrict__ xb) {
    __shared__ float WgL[NEXP * DIM];          // transposed: WgL[e*DIM + ch]
    __shared__ int lcnt[NEXP];
    __shared__ int lbase[NEXP];
    int tid = threadIdx.x;
    for (int i = tid; i < DIM * NEXP; i += 256) {
        int ch = i >> 3, e = i & 7;            // Wg row-major read = coalesced
        WgL[e * DIM + ch] = Wg[i];
    }
    if (tid < NEXP) lcnt[tid] = 0;
    __syncthreads();

    int tl  = tid >> 3;                        // token-in-block 0..31
    int seg = tid & 7;                         // channel segment 0..7 (lane bits 2:0)
    int t   = blockIdx.x * 32 + tl;

    float lg[NEXP] = {0.f, 0.f, 0.f, 0.f, 0.f, 0.f, 0.f, 0.f};
    const float* xr = x + (size_t)t * DIM;
    #pragma unroll
    for (int d4 = 0; d4 < 12; ++d4) {
        float4 v = *(const float4*)(xr + d4 * 32 + seg * 4);
        #pragma unroll
        for (int e = 0; e < NEXP; ++e) {
            float4 w = *(const float4*)&WgL[e * DIM + d4 * 32 + seg * 4];
            lg[e] += v.x * w.x + v.y * w.y + v.z * w.z + v.w * w.w;
        }
        unsigned short rr[4] = {f2bf(v.x), f2bf(v.y), f2bf(v.z), f2bf(v.w)};
        *(uint2*)(xb + (size_t)t * DIM + d4 * 32 + seg * 4) = *(uint2*)rr;
    }
    #pragma unroll
    for (int off = 1; off < 8; off <<= 1)
        #pragma unroll
        for (int e = 0; e < NEXP; ++e)
            lg[e] += __shfl_xor(lg[e], off);

    int p0 = 0, p1 = 0, i0 = 0, i1 = 0;
    float g0 = 0.f, g1 = 0.f;
    if (seg == 0) {
        float v0 = -INFINITY, v1 = -INFINITY;
        #pragma unroll
        for (int e = 0; e < NEXP; ++e) {
            float v = lg[e] + bg[e];
            if (v > v0)      { v1 = v0; i1 = i0; v0 = v; i0 = e; }
            else if (v > v1) { v1 = v;  i1 = e; }
        }
        float e1 = expf(v1 - v0);
        g0 = 1.f / (1.f + e1);
        g1 = e1  / (1.f + e1);
        p0 = atomicAdd(&lcnt[i0], 1);
        p1 = atomicAdd(&lcnt[i1], 1);
    }
    __syncthreads();
    if (tid < NEXP) lbase[tid] = atomicAdd(&cnt[tid], lcnt[tid]);
    __syncthreads();
    if (seg == 0) {
        int o0 = lbase[i0] + p0, o1 = lbase[i1] + p1;
        btok[i0 * N_TOK + o0] = t;
        btok[i1 * N_TOK + o1] = t;
        ((int4*)tokmap)[t] = make_int4(i0, o0, i1, o1);
        ((float2*)gmap)[t] = make_float2(g0, g1);
    }
}

// ---------------------------------------------------------------- GEMM1: h = gelu(xb@W1+b1)
// R15: gather fused into A-staging. Each lane of waves 0-3 owns one token row
// (tok = btok[e][min(tb*128 + wave*32 + (lane&31), cntE-1)], loaded once) and
// cp16's per-lane SOURCE address reads xb[tok][kt*16 + (lane>>5)*8] directly —
// the LDS tile that lands is bit-identical to the old gathered xg tile (HW writes
// lane's 16B at base+lane*16). Eliminates the gather kernel + its 24 MB round trip.
// Pipeline structure = R14's T4 counted-vmcnt depth-2 (BK=48, 3 x 24KB bufs,
// vmcnt(3) in-loop, raw s_barrier, peeled last round), 8 waves, wave-tile 64x32.
__global__ __launch_bounds__(512, 4) void gemm1_kernel(
        const unsigned short* __restrict__ xb, const unsigned short* __restrict__ w1s,
        const float* __restrict__ b1, const int* __restrict__ btok,
        const int* __restrict__ cnt, unsigned short* __restrict__ h) {
    int L = blockIdx.x;                   // e in low 3 bits: XCD pin
    int e = L & 7;
    int r = L >> 3;
    int nb = r % 12;                      // 128-col slice of HID
    int tb = r / 12;                      // 128-token block
    int cntE = cnt[e];
    if (tb * 128 >= cntE) return;

    __shared__ unsigned short stg[3][12288];   // 3 x 24 KB; per buf: A [0..11], B [12..23]

    int tid = threadIdx.x;
    int wave = tid >> 6, lane = tid & 63;
    int m31 = lane & 31, kh = lane >> 5;
    int wm = wave & 1;                    // 64-row half
    int wn = wave >> 1;                   // 32-col quarter (0..3)

    f32x16 acc[2];
    acc[0] = (f32x16){0.f,0.f,0.f,0.f,0.f,0.f,0.f,0.f,0.f,0.f,0.f,0.f,0.f,0.f,0.f,0.f};
    acc[1] = acc[0];

    const unsigned short* wb = w1s + ((size_t)(e * 48 + nb * 4) * 24) * 512;

    // per-wave/lane source base. Waves 0-3: A from xb via per-lane token row
    // (round stride 48 shorts = 3 kt-tiles of 16 k). Waves 4-7: B from w1s
    // (round stride 1536 shorts = 3 tiles of 512).
    const unsigned short* sbase;
    int rstep, qstep;
    if (wave < 4) {
        int posA = tb * 128 + wave * 32 + m31;
        int idxA = (posA < cntE) ? posA : cntE - 1;   // clamp pad rows (masked later)
        int tokA = btok[e * N_TOK + idxA];
        sbase = xb + (size_t)tokA * DIM + kh * 8;
        rstep = 48;  qstep = 16;
    } else {
        sbase = wb + ((size_t)(wave - 4) * 24) * 512 + lane * 8;
        rstep = 1536; qstep = 512;
    }
    int tbase = (wave < 4) ? wave * 3 : 12 + (wave - 4) * 3;   // tile slot in buf

    auto issue = [&](int ks) {
        unsigned short* dst = &stg[ks % 3][tbase * 512];
        const unsigned short* sk = sbase + (size_t)ks * rstep;
        #pragma unroll
        for (int q = 0; q < 3; ++q)
            cp16(sk + q * qstep, dst + q * 512);
    };
    auto consume = [&](int ks) {
        const unsigned short* bufp = stg[ks % 3];
        #pragma unroll
        for (int kt = 0; kt < 3; ++kt) {
            bf16x8 b  = *(const bf16x8*)&bufp[(12 + wn * 3 + kt) * 512 + lane * 8];
            bf16x8 a0 = *(const bf16x8*)&bufp[((wm * 2 + 0) * 3 + kt) * 512 + lane * 8];
            bf16x8 a1 = *(const bf16x8*)&bufp[((wm * 2 + 1) * 3 + kt) * 512 + lane * 8];
            acc[0] = __builtin_amdgcn_mfma_f32_32x32x16_bf16(a0, b, acc[0], 0, 0, 0);
            acc[1] = __builtin_amdgcn_mfma_f32_32x32x16_bf16(a1, b, acc[1], 0, 0, 0);
        }
    };

    issue(0); issue(1);                          // prologue: 6 loads in flight
    for (int ks = 0; ks < 7; ++ks) {             // K = 384 = 8 x BK48; rounds 0..6
        asm volatile("s_waitcnt vmcnt(3) lgkmcnt(0)" ::: "memory");  // round ks landed
        __builtin_amdgcn_sched_barrier(0);
        __builtin_amdgcn_s_barrier();            // raw: ks+1's loads NOT drained
        __builtin_amdgcn_sched_barrier(0);
        if (ks + 2 < 8) issue(ks + 2);
        consume(ks);
    }
    asm volatile("s_waitcnt vmcnt(0) lgkmcnt(0)" ::: "memory");
    __builtin_amdgcn_sched_barrier(0);
    __builtin_amdgcn_s_barrier();
    __builtin_amdgcn_sched_barrier(0);
    consume(7);

    // ---- epilogue: bias + gelu -> per-wave 5 KB region (80B pitch), then h tiles ----
    __syncthreads();                             // all waves done reading stg
    char* hw = (char*)stg + wave * 5120;         // 64 rows x 80 B (40 KB <= 72 KB)
    float bv = b1[e * HID + nb * 128 + wn * 32 + m31];
    #pragma unroll
    for (int s = 0; s < 2; ++s)
        #pragma unroll
        for (int rr = 0; rr < 16; ++rr) {
            int rowl = s * 32 + (rr & 3) + 8 * (rr >> 2) + 4 * kh;   // 0..63 (token row)
            *(unsigned short*)(hw + rowl * 80 + m31 * 2) = f2bf(gelu_exact(acc[s][rr] + bv));
        }
    // read back as A-fragment tiles (lane l: row = l&31, k = (l>>5)*8 + j), store h.
    // wave-private region: compiler inserts the lgkmcnt for the RAW.
    #pragma unroll
    for (int mtl = 0; mtl < 2; ++mtl)
        #pragma unroll
        for (int ktl = 0; ktl < 2; ++ktl) {
            uint4 v = *(const uint4*)(hw + (mtl * 32 + m31) * 80 + (ktl * 16 + kh * 8) * 2);
            int mt = tb * 4 + wm * 2 + mtl;           // token tile (32 rows)
            int kt = nb * 8 + wn * 2 + ktl;           // hid tile (16 k)
            *(uint4*)(h + ((size_t)((e * 72 + mt) * 96 + kt)) * 512 + lane * 8) = v;
        }
}

// ---------------------------------------------------------------- GEMM2: yp = h @ W2
// R14 structure unchanged: T4 counted-vmcnt depth-2 (BK=48, 32 rounds for K=1536,
// 3 x 24KB buffers). Full-K f32 accumulation; epilogue transposes 64x32 per wave
// via 4 KB region (R10-verified, wave*4096 stride).
__global__ __launch_bounds__(512, 4) void gemm2_kernel(
        const unsigned short* __restrict__ h, const unsigned short* __restrict__ w2s,
        const int* __restrict__ cnt, unsigned short* __restrict__ yp) {
    int L = blockIdx.x;
    int e = L & 7;
    int r = L >> 3;
    int nb = r % 3;                        // 128-col slice of OUTD
    int tb = r / 3;                        // 128-token block
    int cntE = cnt[e];
    if (tb * 128 >= cntE) return;

    __shared__ unsigned short stg[3][12288];   // 3 x 24 KB; per buf: A [0..11], B [12..23]

    int tid = threadIdx.x;
    int wave = tid >> 6, lane = tid & 63;
    int m31 = lane & 31, kh = lane >> 5;
    int wm = wave & 1;                     // 64-row half
    int wn = wave >> 1;                    // 32-col quarter (0..3)

    f32x16 acc[2];
    acc[0] = (f32x16){0.f,0.f,0.f,0.f,0.f,0.f,0.f,0.f,0.f,0.f,0.f,0.f,0.f,0.f,0.f,0.f};
    acc[1] = acc[0];

    const unsigned short* xa = h   + ((size_t)(e * 72 + tb * 4) * 96) * 512;
    const unsigned short* wb = w2s + ((size_t)(e * 12 + nb * 4) * 96) * 512;

    const unsigned short* sbase = (wave < 4)
        ? xa + ((size_t)wave * 96) * 512 + lane * 8
        : wb + ((size_t)(wave - 4) * 96) * 512 + lane * 8;
    int tbase = (wave < 4) ? wave * 3 : 12 + (wave - 4) * 3;   // tile slot in buf

    auto issue = [&](int ks) {
        unsigned short* dst = &stg[ks % 3][tbase * 512];
        const unsigned short* sk = sbase + (size_t)ks * 1536;  // 3 kt-tiles x 512
        #pragma unroll
        for (int q = 0; q < 3; ++q)
            cp16(sk + q * 512, dst + q * 512);
    };
    auto consume = [&](int ks) {
        const unsigned short* bufp = stg[ks % 3];
        #pragma unroll
        for (int kt = 0; kt < 3; ++kt) {
            bf16x8 b  = *(const bf16x8*)&bufp[(12 + wn * 3 + kt) * 512 + lane * 8];
            bf16x8 a0 = *(const bf16x8*)&bufp[((wm * 2 + 0) * 3 + kt) * 512 + lane * 8];
            bf16x8 a1 = *(const bf16x8*)&bufp[((wm * 2 + 1) * 3 + kt) * 512 + lane * 8];
            acc[0] = __builtin_amdgcn_mfma_f32_32x32x16_bf16(a0, b, acc[0], 0, 0, 0);
            acc[1] = __builtin_amdgcn_mfma_f32_32x32x16_bf16(a1, b, acc[1], 0, 0, 0);
        }
    };

    issue(0); issue(1);
    for (int ks = 0; ks < 31; ++ks) {          // K = 1536 = 32 x BK48; rounds 0..30
        asm volatile("s_waitcnt vmcnt(3) lgkmcnt(0)" ::: "memory");
        __builtin_amdgcn_sched_barrier(0);
        __builtin_amdgcn_s_barrier();
        __builtin_amdgcn_sched_barrier(0);
        if (ks + 2 < 32) issue(ks + 2);
        consume(ks);
    }
    asm volatile("s_waitcnt vmcnt(0) lgkmcnt(0)" ::: "memory");
    __builtin_amdgcn_sched_barrier(0);
    __builtin_amdgcn_s_barrier();
    __builtin_amdgcn_sched_barrier(0);
    consume(31);

    // ---- epilogue: per-wave 4 KB region (64 rows x 64 B) ----
    __syncthreads();                           // all waves done with stage reads
    char* hw = (char*)stg + wave * 4096;       // 64 rows x 64 B = 4096 B per wave
    #pragma unroll
    for (int s = 0; s < 2; ++s)
        #pragma unroll
        for (int rr = 0; rr < 16; ++rr) {
            int rowl = s * 32 + (rr & 3) + 8 * (rr >> 2) + 4 * kh;   // 0..63
            *(unsigned short*)(hw + rowl * 64 + m31 * 2) = f2bf(acc[s][rr]);
        }
    // read-back: addr = it*1024 + lane*16 (4-way max); store row-major
    #pragma unroll
    for (int it = 0; it < 4; ++it) {
        int rowl = it * 16 + (lane >> 2);
        int cc   = lane & 3;
        uint4 v = *(const uint4*)(hw + rowl * 64 + cc * 16);
        int pos = tb * 128 + wm * 64 + rowl;
        *(uint4*)(yp + (size_t)(e * CAP_TOK + pos) * OUTD + nb * 128 + wn * 32 + cc * 8) = v;
    }
}

// ----------- reduce: out = sum_k g_k * (yp[e_k][pos_k] + b2[e_k]); single full-K partial
__global__ void reduce_kernel(const unsigned short* __restrict__ yp,
                              const int* __restrict__ tokmap, const float* __restrict__ gmap,
                              const float* __restrict__ b2, float* __restrict__ out) {
    int gid = blockIdx.x * 256 + threadIdx.x;      // N_TOK * 48 threads
    int t = gid / 48, q = gid - t * 48;            // q: 8-col group
    int4   tm = ((const int4*)tokmap)[t];
    float2 g  = ((const float2*)gmap)[t];
    const unsigned short* p0 = yp + ((size_t)(tm.x * CAP_TOK + tm.y)) * OUTD + q * 8;
    const unsigned short* p1 = yp + ((size_t)(tm.z * CAP_TOK + tm.w)) * OUTD + q * 8;
    u16x8 a = __builtin_nontemporal_load((const u16x8*)p0);
    u16x8 b = __builtin_nontemporal_load((const u16x8*)p1);
    const float* c0 = &b2[tm.x * OUTD + q * 8];
    const float* c1 = &b2[tm.z * OUTD + q * 8];
    f32x4 r0, r1;
    #pragma unroll
    for (int j = 0; j < 4; ++j) {
        r0[j] = g.x * (bf2f(a[j]) + c0[j]) + g.y * (bf2f(b[j]) + c1[j]);
        r1[j] = g.x * (bf2f(a[4 + j]) + c0[4 + j]) + g.y * (bf2f(b[4 + j]) + c1[4 + j]);
    }
    float* op = &out[(size_t)t * OUTD + q * 8];
    __builtin_nontemporal_store(r0, (f32x4*)op);
    __builtin_nontemporal_store(r1, (f32x4*)(op + 4));
}

// ---------------------------------------------------------------- launch
extern "C" void kernel_launch(void* const* d_in, const int* in_sizes, int n_in,
                              void* d_out, int out_size, void* d_ws, size_t ws_size,
                              hipStream_t stream) {
    const float* x  = (const float*)d_in[0];
    const float* Wg = (const float*)d_in[1];
    const float* bg = (const float*)d_in[2];
    const float* W1 = (const float*)d_in[3];
    const float* b1 = (const float*)d_in[4];
    const float* W2 = (const float*)d_in[5];
    const float* b2 = (const float*)d_in[6];
    float* out = (float*)d_out;

    char* ws = (char*)d_ws;                                    // all offsets 1KB-aligned
    int*            cnt    = (int*)ws;                         // 32 B
    int*            btok   = (int*)(ws + 1024);                // 256 KB
    int*            tokmap = (int*)(ws + 263168);              // 128 KB
    float*          gmap   = (float*)(ws + 394240);            // 64 KB
    unsigned short* xb     = (unsigned short*)(ws + 459776);   // 6.3 MB bf16 x rows
    unsigned short* w1s    = (unsigned short*)(ws + 14615552); // 9.44 MB
    unsigned short* w2s    = (unsigned short*)(ws + 24052736); // 9.44 MB
    unsigned short* h      = (unsigned short*)(ws + 33489920); // 56.6 MB (tiles 8x72x96)
    // yp (13.5 MB bf16) shares xb's slot: gemm2 writes it strictly after gemm1's
    // last xb read (same stream); next iteration's router fully rewrites xb.
    unsigned short* yp     = xb;

    // merged W1+W2 swizzle: (589824 + 589824) / 256 = 4608 blocks exactly
    hipLaunchKernelGGL(swizzle_kernel, dim3(4608), dim3(256), 0, stream,
                       W1, W2, w1s, w2s, cnt);
    hipLaunchKernelGGL(router_kernel, dim3(N_TOK / 32), dim3(256), 0, stream,
                       x, Wg, bg, cnt, btok, tokmap, gmap, xb);
    hipLaunchKernelGGL(gemm1_kernel, dim3(NEXP * 12 * CAP_TB), dim3(512), 0, stream,
                       xb, w1s, b1, btok, cnt, h);
    hipLaunchKernelGGL(gemm2_kernel, dim3(NEXP * 3 * CAP_TB), dim3(512), 0, stream,
                       h, w2s, cnt, yp);
    hipLaunchKernelGGL(reduce_kernel, dim3(N_TOK * 48 / 256), dim3(256), 0, stream,
                       yp, tokmap, gmap, b2, out);
}

// Round 16
// 182.063 us; speedup vs baseline: 1.0246x; 1.0077x over previous
//
#include <hip/hip_runtime.h>
#include <cmath>

#define N_TOK 8192
#define DIM   384
#define NEXP  8
#define HID   1536
#define OUTD  384
#define CAP_MT 72        // 32-row gather tiles per expert (2304 tokens, mean 2048 + 6 sigma)
#define CAP_TOK 2304
#define CAP_TB 18        // 128-row blocks per expert

typedef __attribute__((ext_vector_type(8)))  __bf16 bf16x8;
typedef __attribute__((ext_vector_type(16))) float  f32x16;
typedef __attribute__((ext_vector_type(4)))  float  f32x4;          // nontemporal builtins
typedef __attribute__((ext_vector_type(8)))  unsigned short u16x8;  // nontemporal bf16 loads

__device__ __forceinline__ unsigned short f2bf(float f) {
    unsigned u = __float_as_uint(f);
    u += 0x7FFF + ((u >> 16) & 1);          // round-to-nearest-even
    return (unsigned short)(u >> 16);
}

__device__ __forceinline__ float bf2f(unsigned short s) {
    return __uint_as_float(((unsigned)s) << 16);
}

// R7 lesson: A&S-polynomial gelu with a (non-fast-math) IEEE divide + __expf is SLOWER
// than libm erff (VALUBusy 43->56%). Held at erff since R8 (one-lever discipline).
__device__ __forceinline__ float gelu_exact(float x) {
    return 0.5f * x * (1.0f + erff(x * 0.70710678118654752f));
}

// async global->LDS, 16B per lane; LDS dest = wave-uniform tile base (HW adds lane*16)
__device__ __forceinline__ void cp16(const unsigned short* g, unsigned short* l) {
    __builtin_amdgcn_global_load_lds(
        (const __attribute__((address_space(1))) unsigned int*)g,
        (__attribute__((address_space(3))) unsigned int*)l, 16, 0, 0);
}

// ------------------------- merged W1+W2 swizzle: fp32 [e][K][N] -> B-fragment bf16 tiles
// dst[((e*NT + nt)*KT + kt)*64 + l][j] = bf16(src[e][kt*16 + (l>>5)*8 + j][nt*32 + (l&31)])
// T1 = T2 = 589824 threads -> grid 4608x256 exactly. Block 0 zeroes cnt.
__global__ void swizzle_kernel(const float* __restrict__ W1, const float* __restrict__ W2,
                               unsigned short* __restrict__ w1s, unsigned short* __restrict__ w2s,
                               int* __restrict__ cnt) {
    if (blockIdx.x == 0 && threadIdx.x < NEXP) cnt[threadIdx.x] = 0;
    int gid = blockIdx.x * blockDim.x + threadIdx.x;
    const int T1 = NEXP * 48 * 24 * 64;        // 589824 threads for W1
    const int T2 = NEXP * 12 * 96 * 64;        // 589824 threads for W2
    const float* src; unsigned short* dst; int K, N, NT, KT, g;
    if (gid < T1)           { src = W1; dst = w1s; K = DIM; N = HID;  NT = 48; KT = 24; g = gid; }
    else if (gid < T1 + T2) { src = W2; dst = w2s; K = HID; N = OUTD; NT = 12; KT = 96; g = gid - T1; }
    else return;
    int l  = g & 63;
    int kt = (g >> 6) % KT;
    int nt = ((g >> 6) / KT) % NT;
    int e  = g / (64 * KT * NT);
    const float* s = src + ((size_t)e * K + kt * 16 + (l >> 5) * 8) * N + nt * 32 + (l & 31);
    unsigned short r[8];
    #pragma unroll
    for (int j = 0; j < 8; ++j) r[j] = f2bf(s[(size_t)j * N]);
    *(uint4*)(dst + (size_t)g * 8) = *(uint4*)r;
}

// ---------------------------------------------------------------- router (+ xb emit)
// 256 blocks x 256 thr: 32 tokens/block, 8 threads/token, coalesced 128B chunks;
// Wg staged transposed; __shfl_xor butterfly over seg bits. (R7: verified win.)
// Emits xb[t][d] bf16 row-major (6.3 MB) so gather does pure u16 copies at half
// the read bytes and zero f2bf (R16).
__global__ void router_kernel(const float* __restrict__ x, const float* __restrict__ Wg,
                              const float* __restrict__ bg, int* __restrict__ cnt,
                              int* __restrict__ btok, int* __restrict__ tokmap,
                              float* __restrict__ gmap, unsigned short* __restrict__ xb) {
    __shared__ float WgL[NEXP * DIM];          // transposed: WgL[e*DIM + ch]
    __shared__ int lcnt[NEXP];
    __shared__ int lbase[NEXP];
    int tid = threadIdx.x;
    for (int i = tid; i < DIM * NEXP; i += 256) {
        int ch = i >> 3, e = i & 7;            // Wg row-major read = coalesced
        WgL[e * DIM + ch] = Wg[i];
    }
    if (tid < NEXP) lcnt[tid] = 0;
    __syncthreads();

    int tl  = tid >> 3;                        // token-in-block 0..31
    int seg = tid & 7;                         // channel segment 0..7 (lane bits 2:0)
    int t   = blockIdx.x * 32 + tl;

    float lg[NEXP] = {0.f, 0.f, 0.f, 0.f, 0.f, 0.f, 0.f, 0.f};
    const float* xr = x + (size_t)t * DIM;
    #pragma unroll
    for (int d4 = 0; d4 < 12; ++d4) {
        float4 v = *(const float4*)(xr + d4 * 32 + seg * 4);
        #pragma unroll
        for (int e = 0; e < NEXP; ++e) {
            float4 w = *(const float4*)&WgL[e * DIM + d4 * 32 + seg * 4];
            lg[e] += v.x * w.x + v.y * w.y + v.z * w.z + v.w * w.w;
        }
        unsigned short rr[4] = {f2bf(v.x), f2bf(v.y), f2bf(v.z), f2bf(v.w)};
        *(uint2*)(xb + (size_t)t * DIM + d4 * 32 + seg * 4) = *(uint2*)rr;
    }
    #pragma unroll
    for (int off = 1; off < 8; off <<= 1)
        #pragma unroll
        for (int e = 0; e < NEXP; ++e)
            lg[e] += __shfl_xor(lg[e], off);

    int p0 = 0, p1 = 0, i0 = 0, i1 = 0;
    float g0 = 0.f, g1 = 0.f;
    if (seg == 0) {
        float v0 = -INFINITY, v1 = -INFINITY;
        #pragma unroll
        for (int e = 0; e < NEXP; ++e) {
            float v = lg[e] + bg[e];
            if (v > v0)      { v1 = v0; i1 = i0; v0 = v; i0 = e; }
            else if (v > v1) { v1 = v;  i1 = e; }
        }
        float e1 = expf(v1 - v0);
        g0 = 1.f / (1.f + e1);
        g1 = e1  / (1.f + e1);
        p0 = atomicAdd(&lcnt[i0], 1);
        p1 = atomicAdd(&lcnt[i1], 1);
    }
    __syncthreads();
    if (tid < NEXP) lbase[tid] = atomicAdd(&cnt[tid], lcnt[tid]);
    __syncthreads();
    if (seg == 0) {
        int o0 = lbase[i0] + p0, o1 = lbase[i1] + p1;
        btok[i0 * N_TOK + o0] = t;
        btok[i1 * N_TOK + o1] = t;
        ((int4*)tokmap)[t] = make_int4(i0, o0, i1, o1);
        ((float2*)gmap)[t] = make_float2(g0, g1);
    }
}

// -------------------- gather xb rows into A-fragment tiles (pure u16 copies, R16)
// One scattered pass (vs R15's 12x re-scatter inside gemm1 — that cost gemm1 +5.4us).
__global__ void gather_kernel(const unsigned short* __restrict__ xb,
                              const int* __restrict__ cnt,
                              const int* __restrict__ btok, unsigned short* __restrict__ xg) {
    int mt = blockIdx.x, e = blockIdx.y;
    int cntE = cnt[e];
    if (mt * 32 >= cntE) return;
    int tid = threadIdx.x;                 // 256
    int m = tid & 31, kt0 = tid >> 5;      // 32 x 8
    int pos = mt * 32 + m;
    int idx = (pos < cntE) ? pos : cntE - 1;   // clamp pad rows (masked later)
    int tok = btok[e * N_TOK + idx];
    const unsigned short* xr = xb + (size_t)tok * DIM;
    #pragma unroll
    for (int kk = 0; kk < 3; ++kk) {
        int kt = kt0 + kk * 8;
        #pragma unroll
        for (int kh = 0; kh < 2; ++kh) {
            uint4 v = *(const uint4*)(xr + kt * 16 + kh * 8);
            *(uint4*)(xg + (size_t)(((e * CAP_MT + mt) * 24 + kt) * 64 + kh * 32 + m) * 8) = v;
        }
    }
}

// ---------------------------------------------------------------- GEMM1: h = gelu(xg@W1+b1)
// R14 structure (best-measured 41.3 us): T4 counted-vmcnt depth-2 pipeline. BK=48
// (24KB round, exactly 3 cp16/wave), 3 buffers (72KB). Main loop: s_waitcnt vmcnt(3)
// (round ks landed, round ks+1's loads stay in flight across the raw s_barrier) ->
// s_barrier -> issue(ks+2) -> consume(ks). Last round peeled with vmcnt(0).
// 8 waves, wave-tile 64x32.
__global__ __launch_bounds__(512, 4) void gemm1_kernel(
        const unsigned short* __restrict__ xg, const unsigned short* __restrict__ w1s,
        const float* __restrict__ b1, const int* __restrict__ cnt,
        unsigned short* __restrict__ h) {
    int L = blockIdx.x;                   // e in low 3 bits: XCD pin
    int e = L & 7;
    int r = L >> 3;
    int nb = r % 12;                      // 128-col slice of HID
    int tb = r / 12;                      // 128-token block
    int cntE = cnt[e];
    if (tb * 128 >= cntE) return;

    __shared__ unsigned short stg[3][12288];   // 3 x 24 KB; per buf: A [0..11], B [12..23]

    int tid = threadIdx.x;
    int wave = tid >> 6, lane = tid & 63;
    int m31 = lane & 31, kh = lane >> 5;
    int wm = wave & 1;                    // 64-row half
    int wn = wave >> 1;                   // 32-col quarter (0..3)

    f32x16 acc[2];
    acc[0] = (f32x16){0.f,0.f,0.f,0.f,0.f,0.f,0.f,0.f,0.f,0.f,0.f,0.f,0.f,0.f,0.f,0.f};
    acc[1] = acc[0];

    const unsigned short* xa = xg  + ((size_t)(e * CAP_MT + tb * 4) * 24) * 512;
    const unsigned short* wb = w1s + ((size_t)(e * 48 + nb * 4) * 24) * 512;

    const unsigned short* sbase = (wave < 4)
        ? xa + ((size_t)wave * 24) * 512 + lane * 8
        : wb + ((size_t)(wave - 4) * 24) * 512 + lane * 8;
    int tbase = (wave < 4) ? wave * 3 : 12 + (wave - 4) * 3;   // tile slot in buf

    auto issue = [&](int ks) {
        unsigned short* dst = &stg[ks % 3][tbase * 512];
        const unsigned short* sk = sbase + (size_t)ks * 1536;  // 3 kt-tiles x 512
        #pragma unroll
        for (int q = 0; q < 3; ++q)
            cp16(sk + q * 512, dst + q * 512);
    };
    auto consume = [&](int ks) {
        const unsigned short* bufp = stg[ks % 3];
        #pragma unroll
        for (int kt = 0; kt < 3; ++kt) {
            bf16x8 b  = *(const bf16x8*)&bufp[(12 + wn * 3 + kt) * 512 + lane * 8];
            bf16x8 a0 = *(const bf16x8*)&bufp[((wm * 2 + 0) * 3 + kt) * 512 + lane * 8];
            bf16x8 a1 = *(const bf16x8*)&bufp[((wm * 2 + 1) * 3 + kt) * 512 + lane * 8];
            acc[0] = __builtin_amdgcn_mfma_f32_32x32x16_bf16(a0, b, acc[0], 0, 0, 0);
            acc[1] = __builtin_amdgcn_mfma_f32_32x32x16_bf16(a1, b, acc[1], 0, 0, 0);
        }
    };

    issue(0); issue(1);                          // prologue: 6 loads in flight
    for (int ks = 0; ks < 7; ++ks) {             // K = 384 = 8 x BK48; rounds 0..6
        asm volatile("s_waitcnt vmcnt(3) lgkmcnt(0)" ::: "memory");  // round ks landed
        __builtin_amdgcn_sched_barrier(0);
        __builtin_amdgcn_s_barrier();            // raw: ks+1's loads NOT drained
        __builtin_amdgcn_sched_barrier(0);
        if (ks + 2 < 8) issue(ks + 2);
        consume(ks);
    }
    asm volatile("s_waitcnt vmcnt(0) lgkmcnt(0)" ::: "memory");
    __builtin_amdgcn_sched_barrier(0);
    __builtin_amdgcn_s_barrier();
    __builtin_amdgcn_sched_barrier(0);
    consume(7);

    // ---- epilogue: bias + gelu -> per-wave 5 KB region (80B pitch), then h tiles ----
    __syncthreads();                             // all waves done reading stg
    char* hw = (char*)stg + wave * 5120;         // 64 rows x 80 B (40 KB <= 72 KB)
    float bv = b1[e * HID + nb * 128 + wn * 32 + m31];
    #pragma unroll
    for (int s = 0; s < 2; ++s)
        #pragma unroll
        for (int rr = 0; rr < 16; ++rr) {
            int rowl = s * 32 + (rr & 3) + 8 * (rr >> 2) + 4 * kh;   // 0..63 (token row)
            *(unsigned short*)(hw + rowl * 80 + m31 * 2) = f2bf(gelu_exact(acc[s][rr] + bv));
        }
    // read back as A-fragment tiles (lane l: row = l&31, k = (l>>5)*8 + j), store h.
    // wave-private region: compiler inserts the lgkmcnt for the RAW.
    #pragma unroll
    for (int mtl = 0; mtl < 2; ++mtl)
        #pragma unroll
        for (int ktl = 0; ktl < 2; ++ktl) {
            uint4 v = *(const uint4*)(hw + (mtl * 32 + m31) * 80 + (ktl * 16 + kh * 8) * 2);
            int mt = tb * 4 + wm * 2 + mtl;           // token tile (32 rows)
            int kt = nb * 8 + wn * 2 + ktl;           // hid tile (16 k)
            *(uint4*)(h + ((size_t)((e * CAP_MT + mt) * 96 + kt)) * 512 + lane * 8) = v;
        }
}

// ---------------------------------------------------------------- GEMM2: yp = h @ W2
// R14 structure: T4 counted-vmcnt depth-2 (BK=48, 32 rounds for K=1536, 3 x 24KB
// buffers). Full-K f32 accumulation; epilogue transposes 64x32 per wave via 4 KB
// region (wave*4096 stride).
__global__ __launch_bounds__(512, 4) void gemm2_kernel(
        const unsigned short* __restrict__ h, const unsigned short* __restrict__ w2s,
        const int* __restrict__ cnt, unsigned short* __restrict__ yp) {
    int L = blockIdx.x;
    int e = L & 7;
    int r = L >> 3;
    int nb = r % 3;                        // 128-col slice of OUTD
    int tb = r / 3;                        // 128-token block
    int cntE = cnt[e];
    if (tb * 128 >= cntE) return;

    __shared__ unsigned short stg[3][12288];   // 3 x 24 KB; per buf: A [0..11], B [12..23]

    int tid = threadIdx.x;
    int wave = tid >> 6, lane = tid & 63;
    int m31 = lane & 31, kh = lane >> 5;
    int wm = wave & 1;                     // 64-row half
    int wn = wave >> 1;                    // 32-col quarter (0..3)

    f32x16 acc[2];
    acc[0] = (f32x16){0.f,0.f,0.f,0.f,0.f,0.f,0.f,0.f,0.f,0.f,0.f,0.f,0.f,0.f,0.f,0.f};
    acc[1] = acc[0];

    const unsigned short* xa = h   + ((size_t)(e * CAP_MT + tb * 4) * 96) * 512;
    const unsigned short* wb = w2s + ((size_t)(e * 12 + nb * 4) * 96) * 512;

    const unsigned short* sbase = (wave < 4)
        ? xa + ((size_t)wave * 96) * 512 + lane * 8
        : wb + ((size_t)(wave - 4) * 96) * 512 + lane * 8;
    int tbase = (wave < 4) ? wave * 3 : 12 + (wave - 4) * 3;   // tile slot in buf

    auto issue = [&](int ks) {
        unsigned short* dst = &stg[ks % 3][tbase * 512];
        const unsigned short* sk = sbase + (size_t)ks * 1536;  // 3 kt-tiles x 512
        #pragma unroll
        for (int q = 0; q < 3; ++q)
            cp16(sk + q * 512, dst + q * 512);
    };
    auto consume = [&](int ks) {
        const unsigned short* bufp = stg[ks % 3];
        #pragma unroll
        for (int kt = 0; kt < 3; ++kt) {
            bf16x8 b  = *(const bf16x8*)&bufp[(12 + wn * 3 + kt) * 512 + lane * 8];
            bf16x8 a0 = *(const bf16x8*)&bufp[((wm * 2 + 0) * 3 + kt) * 512 + lane * 8];
            bf16x8 a1 = *(const bf16x8*)&bufp[((wm * 2 + 1) * 3 + kt) * 512 + lane * 8];
            acc[0] = __builtin_amdgcn_mfma_f32_32x32x16_bf16(a0, b, acc[0], 0, 0, 0);
            acc[1] = __builtin_amdgcn_mfma_f32_32x32x16_bf16(a1, b, acc[1], 0, 0, 0);
        }
    };

    issue(0); issue(1);
    for (int ks = 0; ks < 31; ++ks) {          // K = 1536 = 32 x BK48; rounds 0..30
        asm volatile("s_waitcnt vmcnt(3) lgkmcnt(0)" ::: "memory");
        __builtin_amdgcn_sched_barrier(0);
        __builtin_amdgcn_s_barrier();
        __builtin_amdgcn_sched_barrier(0);
        if (ks + 2 < 32) issue(ks + 2);
        consume(ks);
    }
    asm volatile("s_waitcnt vmcnt(0) lgkmcnt(0)" ::: "memory");
    __builtin_amdgcn_sched_barrier(0);
    __builtin_amdgcn_s_barrier();
    __builtin_amdgcn_sched_barrier(0);
    consume(31);

    // ---- epilogue: per-wave 4 KB region (64 rows x 64 B) ----
    __syncthreads();                           // all waves done with stage reads
    char* hw = (char*)stg + wave * 4096;       // 64 rows x 64 B = 4096 B per wave
    #pragma unroll
    for (int s = 0; s < 2; ++s)
        #pragma unroll
        for (int rr = 0; rr < 16; ++rr) {
            int rowl = s * 32 + (rr & 3) + 8 * (rr >> 2) + 4 * kh;   // 0..63
            *(unsigned short*)(hw + rowl * 64 + m31 * 2) = f2bf(acc[s][rr]);
        }
    // read-back: addr = it*1024 + lane*16 (4-way max); store row-major
    #pragma unroll
    for (int it = 0; it < 4; ++it) {
        int rowl = it * 16 + (lane >> 2);
        int cc   = lane & 3;
        uint4 v = *(const uint4*)(hw + rowl * 64 + cc * 16);
        int pos = tb * 128 + wm * 64 + rowl;
        *(uint4*)(yp + (size_t)(e * CAP_TOK + pos) * OUTD + nb * 128 + wn * 32 + cc * 8) = v;
    }
}

// ----------- reduce: out = sum_k g_k * (yp[e_k][pos_k] + b2[e_k]); single full-K partial
__global__ void reduce_kernel(const unsigned short* __restrict__ yp,
                              const int* __restrict__ tokmap, const float* __restrict__ gmap,
                              const float* __restrict__ b2, float* __restrict__ out) {
    int gid = blockIdx.x * 256 + threadIdx.x;      // N_TOK * 48 threads
    int t = gid / 48, q = gid - t * 48;            // q: 8-col group
    int4   tm = ((const int4*)tokmap)[t];
    float2 g  = ((const float2*)gmap)[t];
    const unsigned short* p0 = yp + ((size_t)(tm.x * CAP_TOK + tm.y)) * OUTD + q * 8;
    const unsigned short* p1 = yp + ((size_t)(tm.z * CAP_TOK + tm.w)) * OUTD + q * 8;
    u16x8 a = __builtin_nontemporal_load((const u16x8*)p0);
    u16x8 b = __builtin_nontemporal_load((const u16x8*)p1);
    const float* c0 = &b2[tm.x * OUTD + q * 8];
    const float* c1 = &b2[tm.z * OUTD + q * 8];
    f32x4 r0, r1;
    #pragma unroll
    for (int j = 0; j < 4; ++j) {
        r0[j] = g.x * (bf2f(a[j]) + c0[j]) + g.y * (bf2f(b[j]) + c1[j]);
        r1[j] = g.x * (bf2f(a[4 + j]) + c0[4 + j]) + g.y * (bf2f(b[4 + j]) + c1[4 + j]);
    }
    float* op = &out[(size_t)t * OUTD + q * 8];
    __builtin_nontemporal_store(r0, (f32x4*)op);
    __builtin_nontemporal_store(r1, (f32x4*)(op + 4));
}

// ---------------------------------------------------------------- launch
extern "C" void kernel_launch(void* const* d_in, const int* in_sizes, int n_in,
                              void* d_out, int out_size, void* d_ws, size_t ws_size,
                              hipStream_t stream) {
    const float* x  = (const float*)d_in[0];
    const float* Wg = (const float*)d_in[1];
    const float* bg = (const float*)d_in[2];
    const float* W1 = (const float*)d_in[3];
    const float* b1 = (const float*)d_in[4];
    const float* W2 = (const float*)d_in[5];
    const float* b2 = (const float*)d_in[6];
    float* out = (float*)d_out;

    char* ws = (char*)d_ws;                                    // all offsets 1KB-aligned
    int*            cnt    = (int*)ws;                         // 32 B
    int*            btok   = (int*)(ws + 1024);                // 256 KB
    int*            tokmap = (int*)(ws + 263168);              // 128 KB
    float*          gmap   = (float*)(ws + 394240);            // 64 KB
    unsigned short* xg     = (unsigned short*)(ws + 459776);   // 13.5 MB (tiles 8x72x24)
    unsigned short* w1s    = (unsigned short*)(ws + 14615552); // 9.44 MB
    unsigned short* w2s    = (unsigned short*)(ws + 24052736); // 9.44 MB
    unsigned short* h      = (unsigned short*)(ws + 33489920); // 56.6 MB (tiles 8x72x96)
    unsigned short* xb     = (unsigned short*)(ws + 90113024); // 6.3 MB bf16 x rows
    // yp (13.5 MB bf16) aliases the xg slot: gemm2 writes it strictly after gemm1's
    // last xg read (same stream); next iteration's gather fully rewrites xg.
    unsigned short* yp     = xg;

    // merged W1+W2 swizzle: (589824 + 589824) / 256 = 4608 blocks exactly
    hipLaunchKernelGGL(swizzle_kernel, dim3(4608), dim3(256), 0, stream,
                       W1, W2, w1s, w2s, cnt);
    hipLaunchKernelGGL(router_kernel, dim3(N_TOK / 32), dim3(256), 0, stream,
                       x, Wg, bg, cnt, btok, tokmap, gmap, xb);
    hipLaunchKernelGGL(gather_kernel, dim3(CAP_MT, NEXP), dim3(256), 0, stream,
                       xb, cnt, btok, xg);
    hipLaunchKernelGGL(gemm1_kernel, dim3(NEXP * 12 * CAP_TB), dim3(512), 0, stream,
                       xg, w1s, b1, cnt, h);
    hipLaunchKernelGGL(gemm2_kernel, dim3(NEXP * 3 * CAP_TB), dim3(512), 0, stream,
                       h, w2s, cnt, yp);
    hipLaunchKernelGGL(reduce_kernel, dim3(N_TOK * 48 / 256), dim3(256), 0, stream,
                       yp, tokmap, gmap, b2, out);
}

// Round 17
// 181.487 us; speedup vs baseline: 1.0279x; 1.0032x over previous
//
#include <hip/hip_runtime.h>
#include <cmath>

#define N_TOK 8192
#define DIM   384
#define NEXP  8
#define HID   1536
#define OUTD  384
#define CAP_MT 72        // 32-row gather tiles per expert (2304 tokens, mean 2048 + 6 sigma)
#define CAP_TOK 2304

typedef __attribute__((ext_vector_type(8)))  __bf16 bf16x8;
typedef __attribute__((ext_vector_type(16))) float  f32x16;
typedef __attribute__((ext_vector_type(4)))  float  f32x4;          // nontemporal builtins
typedef __attribute__((ext_vector_type(8)))  unsigned short u16x8;  // nontemporal bf16 loads

__device__ __forceinline__ unsigned short f2bf(float f) {
    unsigned u = __float_as_uint(f);
    u += 0x7FFF + ((u >> 16) & 1);          // round-to-nearest-even
    return (unsigned short)(u >> 16);
}

__device__ __forceinline__ float bf2f(unsigned short s) {
    return __uint_as_float(((unsigned)s) << 16);
}

// R7 lesson: A&S-polynomial gelu with a (non-fast-math) IEEE divide + __expf is SLOWER
// than libm erff (VALUBusy 43->56%). Held at erff since R8.
__device__ __forceinline__ float gelu_exact(float x) {
    return 0.5f * x * (1.0f + erff(x * 0.70710678118654752f));
}

// async global->LDS, 16B per lane; LDS dest = wave-uniform tile base (HW adds lane*16)
__device__ __forceinline__ void cp16(const unsigned short* g, unsigned short* l) {
    __builtin_amdgcn_global_load_lds(
        (const __attribute__((address_space(1))) unsigned int*)g,
        (__attribute__((address_space(3))) unsigned int*)l, 16, 0, 0);
}

// ------------------------- merged W1+W2 swizzle: fp32 [e][K][N] -> B-fragment bf16 tiles
// dst[((e*NT + nt)*KT + kt)*64 + l][j] = bf16(src[e][kt*16 + (l>>5)*8 + j][nt*32 + (l&31)])
// T1 = T2 = 589824 threads -> grid 4608x256 exactly. Block 0 zeroes cnt.
__global__ void swizzle_kernel(const float* __restrict__ W1, const float* __restrict__ W2,
                               unsigned short* __restrict__ w1s, unsigned short* __restrict__ w2s,
                               int* __restrict__ cnt) {
    if (blockIdx.x == 0 && threadIdx.x < NEXP) cnt[threadIdx.x] = 0;
    int gid = blockIdx.x * blockDim.x + threadIdx.x;
    const int T1 = NEXP * 48 * 24 * 64;        // 589824 threads for W1
    const int T2 = NEXP * 12 * 96 * 64;        // 589824 threads for W2
    const float* src; unsigned short* dst; int K, N, NT, KT, g;
    if (gid < T1)           { src = W1; dst = w1s; K = DIM; N = HID;  NT = 48; KT = 24; g = gid; }
    else if (gid < T1 + T2) { src = W2; dst = w2s; K = HID; N = OUTD; NT = 12; KT = 96; g = gid - T1; }
    else return;
    int l  = g & 63;
    int kt = (g >> 6) % KT;
    int nt = ((g >> 6) / KT) % NT;
    int e  = g / (64 * KT * NT);
    const float* s = src + ((size_t)e * K + kt * 16 + (l >> 5) * 8) * N + nt * 32 + (l & 31);
    unsigned short r[8];
    #pragma unroll
    for (int j = 0; j < 8; ++j) r[j] = f2bf(s[(size_t)j * N]);
    *(uint4*)(dst + (size_t)g * 8) = *(uint4*)r;
}

// ---------------------------------------------------------------- router (+ xb emit)
__global__ void router_kernel(const float* __restrict__ x, const float* __restrict__ Wg,
                              const float* __restrict__ bg, int* __restrict__ cnt,
                              int* __restrict__ btok, int* __restrict__ tokmap,
                              float* __restrict__ gmap, unsigned short* __restrict__ xb) {
    __shared__ float WgL[NEXP * DIM];          // transposed: WgL[e*DIM + ch]
    __shared__ int lcnt[NEXP];
    __shared__ int lbase[NEXP];
    int tid = threadIdx.x;
    for (int i = tid; i < DIM * NEXP; i += 256) {
        int ch = i >> 3, e = i & 7;            // Wg row-major read = coalesced
        WgL[e * DIM + ch] = Wg[i];
    }
    if (tid < NEXP) lcnt[tid] = 0;
    __syncthreads();

    int tl  = tid >> 3;                        // token-in-block 0..31
    int seg = tid & 7;                         // channel segment 0..7 (lane bits 2:0)
    int t   = blockIdx.x * 32 + tl;

    float lg[NEXP] = {0.f, 0.f, 0.f, 0.f, 0.f, 0.f, 0.f, 0.f};
    const float* xr = x + (size_t)t * DIM;
    #pragma unroll
    for (int d4 = 0; d4 < 12; ++d4) {
        float4 v = *(const float4*)(xr + d4 * 32 + seg * 4);
        #pragma unroll
        for (int e = 0; e < NEXP; ++e) {
            float4 w = *(const float4*)&WgL[e * DIM + d4 * 32 + seg * 4];
            lg[e] += v.x * w.x + v.y * w.y + v.z * w.z + v.w * w.w;
        }
        unsigned short rr[4] = {f2bf(v.x), f2bf(v.y), f2bf(v.z), f2bf(v.w)};
        *(uint2*)(xb + (size_t)t * DIM + d4 * 32 + seg * 4) = *(uint2*)rr;
    }
    #pragma unroll
    for (int off = 1; off < 8; off <<= 1)
        #pragma unroll
        for (int e = 0; e < NEXP; ++e)
            lg[e] += __shfl_xor(lg[e], off);

    int p0 = 0, p1 = 0, i0 = 0, i1 = 0;
    float g0 = 0.f, g1 = 0.f;
    if (seg == 0) {
        float v0 = -INFINITY, v1 = -INFINITY;
        #pragma unroll
        for (int e = 0; e < NEXP; ++e) {
            float v = lg[e] + bg[e];
            if (v > v0)      { v1 = v0; i1 = i0; v0 = v; i0 = e; }
            else if (v > v1) { v1 = v;  i1 = e; }
        }
        float e1 = expf(v1 - v0);
        g0 = 1.f / (1.f + e1);
        g1 = e1  / (1.f + e1);
        p0 = atomicAdd(&lcnt[i0], 1);
        p1 = atomicAdd(&lcnt[i1], 1);
    }
    __syncthreads();
    if (tid < NEXP) lbase[tid] = atomicAdd(&cnt[tid], lcnt[tid]);
    __syncthreads();
    if (seg == 0) {
        int o0 = lbase[i0] + p0, o1 = lbase[i1] + p1;
        btok[i0 * N_TOK + o0] = t;
        btok[i1 * N_TOK + o1] = t;
        ((int4*)tokmap)[t] = make_int4(i0, o0, i1, o1);
        ((float2*)gmap)[t] = make_float2(g0, g1);
    }
}

// -------------------- gather xb rows into A-fragment tiles (pure u16 copies, R16)
__global__ void gather_kernel(const unsigned short* __restrict__ xb,
                              const int* __restrict__ cnt,
                              const int* __restrict__ btok, unsigned short* __restrict__ xg) {
    int mt = blockIdx.x, e = blockIdx.y;
    int cntE = cnt[e];
    if (mt * 32 >= cntE) return;
    int tid = threadIdx.x;                 // 256
    int m = tid & 31, kt0 = tid >> 5;      // 32 x 8
    int pos = mt * 32 + m;
    int idx = (pos < cntE) ? pos : cntE - 1;   // clamp pad rows (masked later)
    int tok = btok[e * N_TOK + idx];
    const unsigned short* xr = xb + (size_t)tok * DIM;
    #pragma unroll
    for (int kk = 0; kk < 3; ++kk) {
        int kt = kt0 + kk * 8;
        #pragma unroll
        for (int kh = 0; kh < 2; ++kh) {
            uint4 v = *(const uint4*)(xr + kt * 16 + kh * 8);
            *(uint4*)(xg + (size_t)(((e * CAP_MT + mt) * 24 + kt) * 64 + kh * 32 + m) * 8) = v;
        }
    }
}

// ---------------------------------------------------------------- GEMM1: h = gelu(xg@W1+b1)
// R17: wave-tile 64x64 (16 B LDS-read per MFMA vs 24 at 64x32 — the LDS-read pipe is
// gemm1's largest resource term, ~19.5us of 42 by arithmetic). Block 256x128, 8 waves
// (4 row-quarters x 2 col-halves), BK=32, 3 x 24KB bufs, T4 counted-vmcnt(3) depth-2
// (R14 skeleton frozen). Per round each wave stages 3 fixed tiles: A(mt=w>>1,kt=w&1)
// -> slot w; A(mt=w>>1+4) -> slot w+8; B(nt=w>>1) -> slot 16+w.
__global__ __launch_bounds__(512, 4) void gemm1_kernel(
        const unsigned short* __restrict__ xg, const unsigned short* __restrict__ w1s,
        const float* __restrict__ b1, const int* __restrict__ cnt,
        unsigned short* __restrict__ h) {
    int L = blockIdx.x;                   // e in low 3 bits: XCD pin
    int e = L & 7;
    int r = L >> 3;
    int nb = r % 12;                      // 128-col slice of HID
    int tb = r / 12;                      // 256-token block (0..8)
    int cntE = cnt[e];
    if (tb * 256 >= cntE) return;

    __shared__ unsigned short stg[3][12288];   // 3 x 24KB; A tiles [0..15], B tiles [16..23]

    int tid = threadIdx.x;
    int wave = tid >> 6, lane = tid & 63;
    int m31 = lane & 31, kh = lane >> 5;
    int wm = wave & 3;                    // 64-row quarter (0..3)
    int wn = wave >> 2;                   // 64-col half (0..1)

    f32x16 acc[2][2];
    #pragma unroll
    for (int i = 0; i < 2; ++i)
        #pragma unroll
        for (int j = 0; j < 2; ++j)
            acc[i][j] = (f32x16){0.f,0.f,0.f,0.f,0.f,0.f,0.f,0.f,0.f,0.f,0.f,0.f,0.f,0.f,0.f,0.f};

    const unsigned short* xa = xg  + ((size_t)(e * CAP_MT + tb * 8) * 24) * 512;
    const unsigned short* wb = w1s + ((size_t)(e * 48 + nb * 4) * 24) * 512;

    int wk = wave & 1, wh = wave >> 1;    // staging kt / tile-row of this wave
    const unsigned short* srcA1 = xa + ((size_t)wh * 24 + wk) * 512 + lane * 8;
    const unsigned short* srcA2 = srcA1 + (size_t)4 * 24 * 512;   // mt + 4
    const unsigned short* srcB  = wb + ((size_t)wh * 24 + wk) * 512 + lane * 8;

    auto issue = [&](int ks) {
        unsigned short* buf = stg[ks % 3];
        size_t off = (size_t)ks * 1024;        // 2 kt-tiles (1024 shorts) per round
        cp16(srcA1 + off, buf + wave * 512);
        cp16(srcA2 + off, buf + (wave + 8) * 512);
        cp16(srcB  + off, buf + (16 + wave) * 512);
    };
    auto consume = [&](int ks) {
        const unsigned short* buf = stg[ks % 3];
        #pragma unroll
        for (int kt = 0; kt < 2; ++kt) {
            bf16x8 a0  = *(const bf16x8*)&buf[((wm * 2 + 0) * 2 + kt) * 512 + lane * 8];
            bf16x8 a1  = *(const bf16x8*)&buf[((wm * 2 + 1) * 2 + kt) * 512 + lane * 8];
            bf16x8 b0  = *(const bf16x8*)&buf[(16 + (wn * 2 + 0) * 2 + kt) * 512 + lane * 8];
            bf16x8 b1v = *(const bf16x8*)&buf[(16 + (wn * 2 + 1) * 2 + kt) * 512 + lane * 8];
            acc[0][0] = __builtin_amdgcn_mfma_f32_32x32x16_bf16(a0, b0,  acc[0][0], 0, 0, 0);
            acc[0][1] = __builtin_amdgcn_mfma_f32_32x32x16_bf16(a0, b1v, acc[0][1], 0, 0, 0);
            acc[1][0] = __builtin_amdgcn_mfma_f32_32x32x16_bf16(a1, b0,  acc[1][0], 0, 0, 0);
            acc[1][1] = __builtin_amdgcn_mfma_f32_32x32x16_bf16(a1, b1v, acc[1][1], 0, 0, 0);
        }
    };

    issue(0); issue(1);                          // prologue: 6 loads in flight
    for (int ks = 0; ks < 11; ++ks) {            // K = 384 = 12 x BK32; rounds 0..10
        asm volatile("s_waitcnt vmcnt(3) lgkmcnt(0)" ::: "memory");  // round ks landed
        __builtin_amdgcn_sched_barrier(0);
        __builtin_amdgcn_s_barrier();            // raw: round ks+1's loads stay in flight
        __builtin_amdgcn_sched_barrier(0);
        if (ks + 2 < 12) issue(ks + 2);
        consume(ks);
    }
    asm volatile("s_waitcnt vmcnt(0) lgkmcnt(0)" ::: "memory");
    __builtin_amdgcn_sched_barrier(0);
    __builtin_amdgcn_s_barrier();
    __builtin_amdgcn_sched_barrier(0);
    consume(11);

    // ---- epilogue: bias + gelu -> per-wave 64x136B region, then h A-frag tiles ----
    __syncthreads();                             // all waves done reading stg
    char* hw = (char*)stg + wave * 8704;         // 64 rows x 136B (8 x 8704 = 68KB <= 72KB)
    float bv0 = b1[e * HID + nb * 128 + wn * 64 + m31];
    float bv1 = b1[e * HID + nb * 128 + wn * 64 + 32 + m31];
    #pragma unroll
    for (int im = 0; im < 2; ++im)
        #pragma unroll
        for (int in = 0; in < 2; ++in) {
            float bv = in ? bv1 : bv0;
            #pragma unroll
            for (int rr = 0; rr < 16; ++rr) {
                int rowl = im * 32 + (rr & 3) + 8 * (rr >> 2) + 4 * kh;   // 0..63
                *(unsigned short*)(hw + rowl * 136 + (in * 32 + m31) * 2) =
                    f2bf(gelu_exact(acc[im][in][rr] + bv));
            }
        }
    // read back as A-fragment tiles (lane l: row = l&31, k = (l>>5)*8 + j), store h.
    // 136B pitch is 8B-aligned -> uint2 pairs; wave-private RAW (compiler lgkmcnt).
    #pragma unroll
    for (int mtl = 0; mtl < 2; ++mtl)
        #pragma unroll
        for (int ktl = 0; ktl < 4; ++ktl) {
            const char* p = hw + (mtl * 32 + m31) * 136 + (ktl * 16 + kh * 8) * 2;
            uint2 v0 = *(const uint2*)p;
            uint2 v1 = *(const uint2*)(p + 8);
            uint4 v = make_uint4(v0.x, v0.y, v1.x, v1.y);
            int mt = tb * 8 + wm * 2 + mtl;           // token tile (32 rows)
            int kt = nb * 8 + wn * 4 + ktl;           // hid tile (16 k)
            *(uint4*)(h + ((size_t)((e * CAP_MT + mt) * 96 + kt)) * 512 + lane * 8) = v;
        }
}

// ---------------------------------------------------------------- GEMM2: yp = h @ W2
// R17: wave-tile 64x64, 4 waves (256 thr), block 128x128, BK=32 (48 rounds), 3 x 16KB
// bufs (48KB -> 3 blocks/CU), counted-vmcnt(4) depth-2. Per round each wave stages 4
// fixed tiles: A slots w, w+4; B slots 8+w, 8+w+4. Full-K f32 accumulation.
__global__ __launch_bounds__(256, 3) void gemm2_kernel(
        const unsigned short* __restrict__ h, const unsigned short* __restrict__ w2s,
        const int* __restrict__ cnt, unsigned short* __restrict__ yp) {
    int L = blockIdx.x;
    int e = L & 7;
    int r = L >> 3;
    int nb = r % 3;                        // 128-col slice of OUTD
    int tb = r / 3;                        // 128-token block (0..17)
    int cntE = cnt[e];
    if (tb * 128 >= cntE) return;

    __shared__ unsigned short stg[3][8192];    // 3 x 16KB; A tiles [0..7], B tiles [8..15]

    int tid = threadIdx.x;
    int wave = tid >> 6, lane = tid & 63;   // 4 waves
    int m31 = lane & 31, kh = lane >> 5;
    int wm = wave & 1;                     // 64-row half
    int wn = wave >> 1;                    // 64-col half

    f32x16 acc[2][2];
    #pragma unroll
    for (int i = 0; i < 2; ++i)
        #pragma unroll
        for (int j = 0; j < 2; ++j)
            acc[i][j] = (f32x16){0.f,0.f,0.f,0.f,0.f,0.f,0.f,0.f,0.f,0.f,0.f,0.f,0.f,0.f,0.f,0.f};

    const unsigned short* xa = h   + ((size_t)(e * CAP_MT + tb * 4) * 96) * 512;
    const unsigned short* wb = w2s + ((size_t)(e * 12 + nb * 4) * 96) * 512;

    int wk = wave & 1, wh = wave >> 1;
    const unsigned short* srcA1 = xa + ((size_t)wh * 96 + wk) * 512 + lane * 8;
    const unsigned short* srcA2 = srcA1 + (size_t)2 * 96 * 512;   // mt + 2
    const unsigned short* srcB1 = wb + ((size_t)wh * 96 + wk) * 512 + lane * 8;
    const unsigned short* srcB2 = srcB1 + (size_t)2 * 96 * 512;   // nt + 2

    auto issue = [&](int ks) {
        unsigned short* buf = stg[ks % 3];
        size_t off = (size_t)ks * 1024;
        cp16(srcA1 + off, buf + wave * 512);
        cp16(srcA2 + off, buf + (wave + 4) * 512);
        cp16(srcB1 + off, buf + (8 + wave) * 512);
        cp16(srcB2 + off, buf + (8 + wave + 4) * 512);
    };
    auto consume = [&](int ks) {
        const unsigned short* buf = stg[ks % 3];
        #pragma unroll
        for (int kt = 0; kt < 2; ++kt) {
            bf16x8 a0  = *(const bf16x8*)&buf[((wm * 2 + 0) * 2 + kt) * 512 + lane * 8];
            bf16x8 a1  = *(const bf16x8*)&buf[((wm * 2 + 1) * 2 + kt) * 512 + lane * 8];
            bf16x8 b0  = *(const bf16x8*)&buf[(8 + (wn * 2 + 0) * 2 + kt) * 512 + lane * 8];
            bf16x8 b1v = *(const bf16x8*)&buf[(8 + (wn * 2 + 1) * 2 + kt) * 512 + lane * 8];
            acc[0][0] = __builtin_amdgcn_mfma_f32_32x32x16_bf16(a0, b0,  acc[0][0], 0, 0, 0);
            acc[0][1] = __builtin_amdgcn_mfma_f32_32x32x16_bf16(a0, b1v, acc[0][1], 0, 0, 0);
            acc[1][0] = __builtin_amdgcn_mfma_f32_32x32x16_bf16(a1, b0,  acc[1][0], 0, 0, 0);
            acc[1][1] = __builtin_amdgcn_mfma_f32_32x32x16_bf16(a1, b1v, acc[1][1], 0, 0, 0);
        }
    };

    issue(0); issue(1);                          // prologue: 8 loads in flight
    for (int ks = 0; ks < 47; ++ks) {            // K = 1536 = 48 x BK32; rounds 0..46
        asm volatile("s_waitcnt vmcnt(4) lgkmcnt(0)" ::: "memory");  // round ks landed
        __builtin_amdgcn_sched_barrier(0);
        __builtin_amdgcn_s_barrier();
        __builtin_amdgcn_sched_barrier(0);
        if (ks + 2 < 48) issue(ks + 2);
        consume(ks);
    }
    asm volatile("s_waitcnt vmcnt(0) lgkmcnt(0)" ::: "memory");
    __builtin_amdgcn_sched_barrier(0);
    __builtin_amdgcn_s_barrier();
    __builtin_amdgcn_sched_barrier(0);
    consume(47);

    // ---- epilogue: per-wave 64x136B region (4 x 8704 = 34KB <= 48KB) ----
    __syncthreads();                           // all waves done with stage reads
    char* hw = (char*)stg + wave * 8704;
    #pragma unroll
    for (int im = 0; im < 2; ++im)
        #pragma unroll
        for (int in = 0; in < 2; ++in)
            #pragma unroll
            for (int rr = 0; rr < 16; ++rr) {
                int rowl = im * 32 + (rr & 3) + 8 * (rr >> 2) + 4 * kh;   // 0..63
                *(unsigned short*)(hw + rowl * 136 + (in * 32 + m31) * 2) =
                    f2bf(acc[im][in][rr]);
            }
    // read-back: 8 passes of 8 rows x 8 16B-chunks; uint2 pairs (136B pitch, 8B align)
    #pragma unroll
    for (int it = 0; it < 8; ++it) {
        int rowl = it * 8 + (lane >> 3);
        int cc   = lane & 7;
        const char* p = hw + rowl * 136 + cc * 16;
        uint2 v0 = *(const uint2*)p;
        uint2 v1 = *(const uint2*)(p + 8);
        uint4 v = make_uint4(v0.x, v0.y, v1.x, v1.y);
        int pos = tb * 128 + wm * 64 + rowl;
        *(uint4*)(yp + (size_t)(e * CAP_TOK + pos) * OUTD + nb * 128 + wn * 64 + cc * 8) = v;
    }
}

// ----------- reduce: out = sum_k g_k * (yp[e_k][pos_k] + b2[e_k]); single full-K partial
__global__ void reduce_kernel(const unsigned short* __restrict__ yp,
                              const int* __restrict__ tokmap, const float* __restrict__ gmap,
                              const float* __restrict__ b2, float* __restrict__ out) {
    int gid = blockIdx.x * 256 + threadIdx.x;      // N_TOK * 48 threads
    int t = gid / 48, q = gid - t * 48;            // q: 8-col group
    int4   tm = ((const int4*)tokmap)[t];
    float2 g  = ((const float2*)gmap)[t];
    const unsigned short* p0 = yp + ((size_t)(tm.x * CAP_TOK + tm.y)) * OUTD + q * 8;
    const unsigned short* p1 = yp + ((size_t)(tm.z * CAP_TOK + tm.w)) * OUTD + q * 8;
    u16x8 a = __builtin_nontemporal_load((const u16x8*)p0);
    u16x8 b = __builtin_nontemporal_load((const u16x8*)p1);
    const float* c0 = &b2[tm.x * OUTD + q * 8];
    const float* c1 = &b2[tm.z * OUTD + q * 8];
    f32x4 r0, r1;
    #pragma unroll
    for (int j = 0; j < 4; ++j) {
        r0[j] = g.x * (bf2f(a[j]) + c0[j]) + g.y * (bf2f(b[j]) + c1[j]);
        r1[j] = g.x * (bf2f(a[4 + j]) + c0[4 + j]) + g.y * (bf2f(b[4 + j]) + c1[4 + j]);
    }
    float* op = &out[(size_t)t * OUTD + q * 8];
    __builtin_nontemporal_store(r0, (f32x4*)op);
    __builtin_nontemporal_store(r1, (f32x4*)(op + 4));
}

// ---------------------------------------------------------------- launch
extern "C" void kernel_launch(void* const* d_in, const int* in_sizes, int n_in,
                              void* d_out, int out_size, void* d_ws, size_t ws_size,
                              hipStream_t stream) {
    const float* x  = (const float*)d_in[0];
    const float* Wg = (const float*)d_in[1];
    const float* bg = (const float*)d_in[2];
    const float* W1 = (const float*)d_in[3];
    const float* b1 = (const float*)d_in[4];
    const float* W2 = (const float*)d_in[5];
    const float* b2 = (const float*)d_in[6];
    float* out = (float*)d_out;

    char* ws = (char*)d_ws;                                    // all offsets 1KB-aligned
    int*            cnt    = (int*)ws;                         // 32 B
    int*            btok   = (int*)(ws + 1024);                // 256 KB
    int*            tokmap = (int*)(ws + 263168);              // 128 KB
    float*          gmap   = (float*)(ws + 394240);            // 64 KB
    unsigned short* xg     = (unsigned short*)(ws + 459776);   // 13.5 MB (tiles 8x72x24)
    unsigned short* w1s    = (unsigned short*)(ws + 14615552); // 9.44 MB
    unsigned short* w2s    = (unsigned short*)(ws + 24052736); // 9.44 MB
    unsigned short* h      = (unsigned short*)(ws + 33489920); // 56.6 MB (tiles 8x72x96)
    unsigned short* xb     = (unsigned short*)(ws + 90113024); // 6.3 MB bf16 x rows
    // yp (13.5 MB bf16) aliases the xg slot: gemm2 writes it strictly after gemm1's
    // last xg read (same stream); next iteration's gather fully rewrites xg.
    unsigned short* yp     = xg;

    // merged W1+W2 swizzle: (589824 + 589824) / 256 = 4608 blocks exactly
    hipLaunchKernelGGL(swizzle_kernel, dim3(4608), dim3(256), 0, stream,
                       W1, W2, w1s, w2s, cnt);
    hipLaunchKernelGGL(router_kernel, dim3(N_TOK / 32), dim3(256), 0, stream,
                       x, Wg, bg, cnt, btok, tokmap, gmap, xb);
    hipLaunchKernelGGL(gather_kernel, dim3(CAP_MT, NEXP), dim3(256), 0, stream,
                       xb, cnt, btok, xg);
    hipLaunchKernelGGL(gemm1_kernel, dim3(NEXP * 12 * 9), dim3(512), 0, stream,
                       xg, w1s, b1, cnt, h);
    hipLaunchKernelGGL(gemm2_kernel, dim3(NEXP * 3 * 18), dim3(256), 0, stream,
                       h, w2s, cnt, yp);
    hipLaunchKernelGGL(reduce_kernel, dim3(N_TOK * 48 / 256), dim3(256), 0, stream,
                       yp, tokmap, gmap, b2, out);
}